// Round 1
// baseline (1456.375 us; speedup 1.0000x reference)
//
#include <hip/hip_runtime.h>
#include <cstddef>
#include <cstdint>

// STGCN fp32 baseline. Structure:
//   CSR build (detect edge dtype, degree histogram, block scan, fill)
//   weight pre-transpose: conv tw[l][o][c][k] -> wt[l][k][c][o]; [wl|wr] -> wt2[l][j][o]; clf_w -> cwt[c][o]
//   per layer: k_conv (GEMM-style, A staged in LDS transposed) -> k_agg (CSR mean gather) -> k_gemm (+BN+ReLU)
//   k_clf: classifier GEMM + fused log_softmax
// All fp32 vector FMA (no fp32 MFMA on CDNA4).

#define N_NODES 50000
#define FDIM    128
#define OUTC    64
#define NLAYER  3
#define KW      9
#define PADW    4
#define NEDGE   600000
#define BN_EPS  1e-5f

__device__ __forceinline__ float relu_(float v){ return v > 0.f ? v : 0.f; }

// ---------------- edge dtype detect + CSR build ----------------

__global__ void k_detect(const int* __restrict__ ei, int* __restrict__ flag){
  // If edge_index is int64, every odd int32 word (high word) of the first 64
  // src entries is 0. If int32, those words are random node ids (p(all 0) ~ 0).
  int t = threadIdx.x;
  unsigned long long b = __ballot(ei[2*t+1] == 0);
  if (t == 0) flag[0] = (b == ~0ull) ? 1 : 0;
}

__global__ void k_zero(int* __restrict__ p, int n){
  int i = blockIdx.x*256 + threadIdx.x;
  if (i < n) p[i] = 0;
}

__global__ void k_deg(const int* __restrict__ ei, const int* __restrict__ flag, int* __restrict__ deg){
  int e = blockIdx.x*256 + threadIdx.x;
  if (e >= NEDGE) return;
  int d = flag[0] ? ei[2*(NEDGE+e)] : ei[NEDGE+e];
  atomicAdd(&deg[d], 1);
}

__global__ void k_scan1(const int* __restrict__ deg, int* __restrict__ rp, int* __restrict__ bsums){
  __shared__ int sd[256];
  int t = threadIdx.x, base = blockIdx.x*1024 + t*4;
  int v0=0,v1=0,v2=0,v3=0;
  if (base+3 < N_NODES){ int4 q = *(const int4*)(deg+base); v0=q.x; v1=q.y; v2=q.z; v3=q.w; }
  else {
    if (base   < N_NODES) v0 = deg[base];
    if (base+1 < N_NODES) v1 = deg[base+1];
    if (base+2 < N_NODES) v2 = deg[base+2];
    if (base+3 < N_NODES) v3 = deg[base+3];
  }
  int s = v0+v1+v2+v3;
  sd[t] = s; __syncthreads();
  #pragma unroll
  for (int o=1;o<256;o<<=1){
    int x = (t>=o) ? sd[t-o] : 0;
    __syncthreads();
    sd[t] += x;
    __syncthreads();
  }
  int excl = sd[t]-s;
  if (base   < N_NODES) rp[base  ] = excl;
  if (base+1 < N_NODES) rp[base+1] = excl+v0;
  if (base+2 < N_NODES) rp[base+2] = excl+v0+v1;
  if (base+3 < N_NODES) rp[base+3] = excl+v0+v1+v2;
  if (t==255) bsums[blockIdx.x] = sd[255];
}

__global__ void k_scan2(int* __restrict__ bsums, int nb){
  if (threadIdx.x==0 && blockIdx.x==0){
    int run = 0;
    for (int i=0;i<nb;i++){ int x = bsums[i]; bsums[i] = run; run += x; }
  }
}

__global__ void k_scan3(int* __restrict__ rp, int* __restrict__ cur, float* __restrict__ idg,
                        const int* __restrict__ deg, const int* __restrict__ bsums){
  int i = blockIdx.x*256 + threadIdx.x;
  if (i < N_NODES){
    int r = rp[i] + bsums[i>>10];
    rp[i] = r; cur[i] = r;
    int d = deg[i];
    idg[i] = (d>0) ? 1.0f/(float)d : 0.0f;
  } else if (i == N_NODES){
    rp[N_NODES] = NEDGE;
  }
}

__global__ void k_fill(const int* __restrict__ ei, const int* __restrict__ flag,
                       int* __restrict__ cur, int* __restrict__ col){
  int e = blockIdx.x*256 + threadIdx.x;
  if (e >= NEDGE) return;
  int s,d;
  if (flag[0]){ s = ei[2*e]; d = ei[2*(NEDGE+e)]; }
  else        { s = ei[e];   d = ei[NEDGE+e];   }
  int pos = atomicAdd(&cur[d], 1);
  col[pos] = s;
}

// ---------------- weight pre-transpose ----------------
// wt  [l][k][c][o] <- tw[l][o][c][k]         (442368)
// wt2 [l][j][o]    <- j<128 ? wl[l][o][j] : wr[l][o][j-128]   (98304)
// cwt [c][o]       <- clf_w[o][c]            (8192)

__global__ void k_wt(const float* __restrict__ tw, const float* __restrict__ wl,
                     const float* __restrict__ wr, const float* __restrict__ cw,
                     float* __restrict__ wt, float* __restrict__ wt2, float* __restrict__ cwt){
  int i = blockIdx.x*256 + threadIdx.x;
  const int T1 = NLAYER*KW*128*128;   // 442368
  const int T2 = NLAYER*256*128;      // 98304
  const int T3 = 128*64;              // 8192
  if (i < T1){
    int o = i & 127, c = (i>>7)&127, kl = i>>14;
    int k = kl % KW, l = kl / KW;
    wt[i] = tw[(((l*128+o)*128+c)*KW)+k];
  } else if (i < T1+T2){
    int j2 = i - T1;
    int o = j2 & 127, j = (j2>>7)&255, l = j2>>15;
    wt2[j2] = (j<128) ? wl[(l*128+o)*128 + j] : wr[(l*128+o)*128 + (j-128)];
  } else if (i < T1+T2+T3){
    int j3 = i - (T1+T2);
    int o = j3 & 63, c = j3 >> 6;
    cwt[j3] = cw[o*128 + c];
  }
}

// ---------------- staging helper ----------------

template<int ST>
__device__ __forceinline__ void stage64(float (*As)[ST], const float* __restrict__ src, int n0, int t){
  for (int u=t; u<64*32; u+=256){
    int row = u>>5, c4 = (u&31)*4;
    int gn = n0 + row;
    float4 v = make_float4(0.f,0.f,0.f,0.f);
    if (gn < N_NODES) v = *(const float4*)(src + (size_t)gn*FDIM + c4);
    As[c4  ][row] = v.x; As[c4+1][row] = v.y; As[c4+2][row] = v.z; As[c4+3][row] = v.w;
  }
}

// ---------------- conv (temporal Conv1d over node axis) ----------------
// Tile: 64 nodes x 128 outs, 256 threads, per-thread 4 nodes (stride 16) x 8 outs.
// LDS: x window [c][row] stride 77 -> broadcast-conflict-free compute reads.

__global__ __launch_bounds__(256) void k_conv(const float* __restrict__ xin, const float* __restrict__ wt,
                                              const float* __restrict__ tb, float* __restrict__ hout){
  __shared__ float As[128][77];
  const int t = threadIdx.x;
  const int n0 = blockIdx.x*64;
  for (int u=t; u<72*32; u+=256){
    int row = u>>5, c4 = (u&31)*4;
    int gn = n0 - PADW + row;
    float4 v = make_float4(0.f,0.f,0.f,0.f);
    if (gn >= 0 && gn < N_NODES) v = *(const float4*)(xin + (size_t)gn*FDIM + c4);
    As[c4  ][row] = v.x; As[c4+1][row] = v.y; As[c4+2][row] = v.z; As[c4+3][row] = v.w;
  }
  __syncthreads();
  const int ng = t & 15, ob = (t>>4)*8;
  float acc[4][8];
  #pragma unroll
  for (int i=0;i<4;i++)
    #pragma unroll
    for (int j=0;j<8;j++) acc[i][j] = 0.f;

  #pragma unroll
  for (int k=0;k<KW;k++){
    const float* wk = wt + k*16384;
    #pragma unroll 2
    for (int c=0;c<128;c++){
      float aa[4];
      aa[0] = As[c][ng+k];
      aa[1] = As[c][ng+k+16];
      aa[2] = As[c][ng+k+32];
      aa[3] = As[c][ng+k+48];
      float4 b0 = *(const float4*)(wk + c*128 + ob);
      float4 b1 = *(const float4*)(wk + c*128 + ob + 4);
      float bb[8] = {b0.x,b0.y,b0.z,b0.w,b1.x,b1.y,b1.z,b1.w};
      #pragma unroll
      for (int i=0;i<4;i++)
        #pragma unroll
        for (int j=0;j<8;j++) acc[i][j] = fmaf(aa[i], bb[j], acc[i][j]);
    }
  }
  float4 t0 = *(const float4*)(tb+ob), t1 = *(const float4*)(tb+ob+4);
  float tbv[8] = {t0.x,t0.y,t0.z,t0.w,t1.x,t1.y,t1.z,t1.w};
  #pragma unroll
  for (int i=0;i<4;i++){
    int n = n0 + ng + 16*i;
    if (n < N_NODES){
      float4 r0, r1;
      r0.x = relu_(acc[i][0]+tbv[0]); r0.y = relu_(acc[i][1]+tbv[1]);
      r0.z = relu_(acc[i][2]+tbv[2]); r0.w = relu_(acc[i][3]+tbv[3]);
      r1.x = relu_(acc[i][4]+tbv[4]); r1.y = relu_(acc[i][5]+tbv[5]);
      r1.z = relu_(acc[i][6]+tbv[6]); r1.w = relu_(acc[i][7]+tbv[7]);
      *(float4*)(hout + (size_t)n*FDIM + ob)     = r0;
      *(float4*)(hout + (size_t)n*FDIM + ob + 4) = r1;
    }
  }
}

// ---------------- SAGE mean aggregation (CSR gather) ----------------

__global__ __launch_bounds__(256) void k_agg(const float* __restrict__ h, const int* __restrict__ rp,
                                             const int* __restrict__ col, const float* __restrict__ idg,
                                             float* __restrict__ agg){
  int n = blockIdx.x*4 + (threadIdx.x>>6);
  int lane = threadIdx.x & 63;
  if (n >= N_NODES) return;
  int s0 = rp[n], s1 = rp[n+1];
  float ax = 0.f, ay = 0.f;
  for (int e=s0;e<s1;e++){
    int s = col[e];
    float2 v = *(const float2*)(h + (size_t)s*FDIM + lane*2);
    ax += v.x; ay += v.y;
  }
  float w = idg[n];
  float2 r; r.x = ax*w; r.y = ay*w;
  *(float2*)(agg + (size_t)n*FDIM + lane*2) = r;
}

// ---------------- SAGE linear + BN(eval) + ReLU ----------------
// out[n][o] = relu( s[o]*(agg@wl.T + h@wr.T)[n][o] + c[o] ),  K split into two 128-phases.

__global__ __launch_bounds__(256) void k_gemm(const float* __restrict__ aggv, const float* __restrict__ h,
    const float* __restrict__ w2, const float* __restrict__ bl, const float* __restrict__ bng,
    const float* __restrict__ bnb, const float* __restrict__ bnm, const float* __restrict__ bnv,
    float* __restrict__ xout){
  __shared__ float As[128][65];
  const int t = threadIdx.x, n0 = blockIdx.x*64;
  const int ng = t & 15, ob = (t>>4)*8;
  float acc[4][8];
  #pragma unroll
  for (int i=0;i<4;i++)
    #pragma unroll
    for (int j=0;j<8;j++) acc[i][j] = 0.f;

  // phase 1: agg part (j = 0..127 -> wl)
  stage64<65>(As, aggv, n0, t);
  __syncthreads();
  #pragma unroll 2
  for (int c=0;c<128;c++){
    float aa[4] = {As[c][ng], As[c][ng+16], As[c][ng+32], As[c][ng+48]};
    float4 b0 = *(const float4*)(w2 + c*128 + ob);
    float4 b1 = *(const float4*)(w2 + c*128 + ob + 4);
    float bb[8] = {b0.x,b0.y,b0.z,b0.w,b1.x,b1.y,b1.z,b1.w};
    #pragma unroll
    for (int i=0;i<4;i++)
      #pragma unroll
      for (int j=0;j<8;j++) acc[i][j] = fmaf(aa[i], bb[j], acc[i][j]);
  }
  __syncthreads();
  // phase 2: h part (j = 128..255 -> wr)
  stage64<65>(As, h, n0, t);
  __syncthreads();
  #pragma unroll 2
  for (int c=0;c<128;c++){
    float aa[4] = {As[c][ng], As[c][ng+16], As[c][ng+32], As[c][ng+48]};
    float4 b0 = *(const float4*)(w2 + (128+c)*128 + ob);
    float4 b1 = *(const float4*)(w2 + (128+c)*128 + ob + 4);
    float bb[8] = {b0.x,b0.y,b0.z,b0.w,b1.x,b1.y,b1.z,b1.w};
    #pragma unroll
    for (int i=0;i<4;i++)
      #pragma unroll
      for (int j=0;j<8;j++) acc[i][j] = fmaf(aa[i], bb[j], acc[i][j]);
  }

  float4 g0 = *(const float4*)(bng+ob), g1 = *(const float4*)(bng+ob+4);
  float4 o0 = *(const float4*)(bnb+ob), o1 = *(const float4*)(bnb+ob+4);
  float4 m0 = *(const float4*)(bnm+ob), m1 = *(const float4*)(bnm+ob+4);
  float4 v0 = *(const float4*)(bnv+ob), v1 = *(const float4*)(bnv+ob+4);
  float4 l0 = *(const float4*)(bl +ob), l1 = *(const float4*)(bl +ob+4);
  float gg[8]={g0.x,g0.y,g0.z,g0.w,g1.x,g1.y,g1.z,g1.w};
  float bbv[8]={o0.x,o0.y,o0.z,o0.w,o1.x,o1.y,o1.z,o1.w};
  float mm[8]={m0.x,m0.y,m0.z,m0.w,m1.x,m1.y,m1.z,m1.w};
  float vv[8]={v0.x,v0.y,v0.z,v0.w,v1.x,v1.y,v1.z,v1.w};
  float ll[8]={l0.x,l0.y,l0.z,l0.w,l1.x,l1.y,l1.z,l1.w};
  float sj[8], cj[8];
  #pragma unroll
  for (int j=0;j<8;j++){
    sj[j] = gg[j]*rsqrtf(vv[j]+BN_EPS);
    cj[j] = bbv[j] + sj[j]*(ll[j]-mm[j]);
  }
  #pragma unroll
  for (int i=0;i<4;i++){
    int n = n0 + ng + 16*i;
    if (n < N_NODES){
      float4 r0, r1;
      r0.x = relu_(sj[0]*acc[i][0]+cj[0]); r0.y = relu_(sj[1]*acc[i][1]+cj[1]);
      r0.z = relu_(sj[2]*acc[i][2]+cj[2]); r0.w = relu_(sj[3]*acc[i][3]+cj[3]);
      r1.x = relu_(sj[4]*acc[i][4]+cj[4]); r1.y = relu_(sj[5]*acc[i][5]+cj[5]);
      r1.z = relu_(sj[6]*acc[i][6]+cj[6]); r1.w = relu_(sj[7]*acc[i][7]+cj[7]);
      *(float4*)(xout + (size_t)n*FDIM + ob)     = r0;
      *(float4*)(xout + (size_t)n*FDIM + ob + 4) = r1;
    }
  }
}

// ---------------- classifier + log_softmax ----------------
// Tile 64 nodes x 64 outs; logits staged in LDS for the row reduce.

__global__ __launch_bounds__(256) void k_clf(const float* __restrict__ x, const float* __restrict__ cwt,
                                             const float* __restrict__ cb, float* __restrict__ out){
  __shared__ float As[128][68];
  __shared__ float mxl[64];
  const int t = threadIdx.x, n0 = blockIdx.x*64;
  const int ng = t & 15, og = t>>4;          // og: 16 groups of 4 outputs
  float acc[4][4];
  #pragma unroll
  for (int i=0;i<4;i++)
    #pragma unroll
    for (int j=0;j<4;j++) acc[i][j] = 0.f;

  stage64<68>(As, x, n0, t);
  __syncthreads();
  #pragma unroll 2
  for (int c=0;c<128;c++){
    float aa[4] = {As[c][ng], As[c][ng+16], As[c][ng+32], As[c][ng+48]};
    float4 b = *(const float4*)(cwt + c*64 + og*4);
    float bb[4] = {b.x,b.y,b.z,b.w};
    #pragma unroll
    for (int i=0;i<4;i++)
      #pragma unroll
      for (int j=0;j<4;j++) acc[i][j] = fmaf(aa[i], bb[j], acc[i][j]);
  }
  __syncthreads();   // done reading As; reuse rows [0,64) as the logits tile
  float4 cb4 = *(const float4*)(cb + og*4);
  float cbv[4] = {cb4.x,cb4.y,cb4.z,cb4.w};
  #pragma unroll
  for (int i=0;i<4;i++)
    #pragma unroll
    for (int j=0;j<4;j++) As[ng+16*i][og*4+j] = acc[i][j] + cbv[j];
  __syncthreads();
  if (t < 64){
    float mx = -1e30f;
    #pragma unroll 8
    for (int o=0;o<64;o++) mx = fmaxf(mx, As[t][o]);
    float se = 0.f;
    #pragma unroll 8
    for (int o=0;o<64;o++) se += expf(As[t][o]-mx);
    mxl[t] = mx + logf(se);
  }
  __syncthreads();
  #pragma unroll
  for (int v=0;v<4;v++){
    int q = t + v*256;
    int r = q>>4, o4 = (q&15)*4;
    int n = n0 + r;
    if (n < N_NODES){
      float4 L = *(const float4*)&As[r][o4];
      float m = mxl[r];
      float4 w; w.x = L.x-m; w.y = L.y-m; w.z = L.z-m; w.w = L.w-m;
      *(float4*)(out + (size_t)n*OUTC + o4) = w;
    }
  }
}

// ---------------- launch ----------------

extern "C" void kernel_launch(void* const* d_in, const int* in_sizes, int n_in,
                              void* d_out, int out_size, void* d_ws, size_t ws_size,
                              hipStream_t stream) {
  const float* x   = (const float*)d_in[0];
  const int*   ei  = (const int*)  d_in[1];
  const float* tw  = (const float*)d_in[2];
  const float* tb  = (const float*)d_in[3];
  const float* wl  = (const float*)d_in[4];
  const float* bl  = (const float*)d_in[5];
  const float* wr  = (const float*)d_in[6];
  const float* bng = (const float*)d_in[7];
  const float* bnb = (const float*)d_in[8];
  const float* bnm = (const float*)d_in[9];
  const float* bnv = (const float*)d_in[10];
  const float* cw  = (const float*)d_in[11];
  const float* cb  = (const float*)d_in[12];
  float* out = (float*)d_out;
  char* ws = (char*)d_ws;

  // workspace layout (256B-aligned)
  auto align256 = [](size_t v){ return (v + 255) & ~(size_t)255; };
  size_t off = 0;
  auto take = [&](size_t bytes){ size_t o = off; off += align256(bytes); return o; };
  float* xbuf  = (float*)(ws + take((size_t)N_NODES*FDIM*4));        // 25.6 MB
  float* hbuf  = (float*)(ws + take((size_t)N_NODES*FDIM*4));        // 25.6 MB
  float* aggb  = (float*)(ws + take((size_t)N_NODES*FDIM*4));        // 25.6 MB
  float* wt    = (float*)(ws + take((size_t)NLAYER*KW*128*128*4));   // 1.77 MB
  float* wt2   = (float*)(ws + take((size_t)NLAYER*256*128*4));      // 393 KB
  float* cwt   = (float*)(ws + take((size_t)128*64*4));              // 32 KB
  int*   deg   = (int*)  (ws + take((size_t)N_NODES*4));
  int*   rp    = (int*)  (ws + take((size_t)(N_NODES+1)*4));
  int*   cur   = (int*)  (ws + take((size_t)N_NODES*4));
  int*   col   = (int*)  (ws + take((size_t)NEDGE*4));
  float* idg   = (float*)(ws + take((size_t)N_NODES*4));
  int*   bsums = (int*)  (ws + take(256));
  int*   flag  = (int*)  (ws + take(256));
  (void)ws_size; (void)in_sizes; (void)n_in; (void)out_size;

  const int NB_N   = (N_NODES + 255)/256;       // 196
  const int NB_E   = (NEDGE   + 255)/256;       // 2344
  const int NB_SC  = (N_NODES + 1023)/1024;     // 49
  const int NB_T   = (N_NODES + 63)/64;         // 782
  const int NB_WT  = (NLAYER*KW*128*128 + NLAYER*256*128 + 128*64)/256; // 2144

  // CSR build
  k_detect<<<1, 64, 0, stream>>>(ei, flag);
  k_zero  <<<NB_N, 256, 0, stream>>>(deg, N_NODES);
  k_deg   <<<NB_E, 256, 0, stream>>>(ei, flag, deg);
  k_scan1 <<<NB_SC, 256, 0, stream>>>(deg, rp, bsums);
  k_scan2 <<<1, 64, 0, stream>>>(bsums, NB_SC);
  k_scan3 <<<NB_N+1, 256, 0, stream>>>(rp, cur, idg, deg, bsums);
  k_fill  <<<NB_E, 256, 0, stream>>>(ei, flag, cur, col);
  // weight transpose
  k_wt    <<<NB_WT, 256, 0, stream>>>(tw, wl, wr, cw, wt, wt2, cwt);

  for (int l=0; l<NLAYER; l++){
    const float* xin = (l==0) ? x : xbuf;
    k_conv<<<NB_T, 256, 0, stream>>>(xin, wt + (size_t)l*KW*128*128, tb + l*128, hbuf);
    k_agg <<<N_NODES/4, 256, 0, stream>>>(hbuf, rp, col, idg, aggb);
    k_gemm<<<NB_T, 256, 0, stream>>>(aggb, hbuf, wt2 + (size_t)l*256*128,
                                     bl + l*128, bng + l*128, bnb + l*128,
                                     bnm + l*128, bnv + l*128, xbuf);
  }
  k_clf<<<NB_T, 256, 0, stream>>>(xbuf, cwt, cb, out);
}

// Round 6
// 606.494 us; speedup vs baseline: 2.4013x; 2.4013x over previous
//
#include <hip/hip_runtime.h>
#include <cstddef>
#include <cstdint>

// STGCN v2: conv + SAGE-linear moved to MFMA bf16 split-fp32 (3-term emulation).
//   - conv: block 128 nodes x 128 outs, 4 waves, wave-tile 128x32, K=9*128 in
//     two 64-channel LDS halves (34.8 KB, XOR-swizzled, hi/lo bf16 planes).
//   - weights prepacked on-device into MFMA fragment-ready 1KB chunks.
//   - SAGE gemm: same structure, K=256 ([agg|h]) in 4 phases of 64 channels.
//   - BN+ReLU / bias+ReLU fused in epilogues. CSR build + agg + clf unchanged.

#define N_NODES 50000
#define FDIM    128
#define OUTC    64
#define NLAYER  3
#define KW      9
#define PADW    4
#define NEDGE   600000
#define BN_EPS  1e-5f

typedef short bf16x8 __attribute__((ext_vector_type(8)));
typedef float f32x4  __attribute__((ext_vector_type(4)));

__device__ __forceinline__ float relu_(float v){ return v > 0.f ? v : 0.f; }

__device__ __forceinline__ unsigned short bf_rne(float x){
  unsigned u = __float_as_uint(x);
  unsigned r = u + 0x7fff + ((u >> 16) & 1);
  return (unsigned short)(r >> 16);
}
// split x into hi (bf16) + rem
__device__ __forceinline__ unsigned short bf_hi(float x, float& rem){
  unsigned short h = bf_rne(x);
  rem = x - __uint_as_float(((unsigned)h) << 16);
  return h;
}
// convert 8 floats -> packed hi int4 + lo int4
__device__ __forceinline__ void cvt8(const float4& f0, const float4& f1, int4& hv, int4& lv){
  float f[8] = {f0.x,f0.y,f0.z,f0.w,f1.x,f1.y,f1.z,f1.w};
  unsigned short h[8], l[8];
  #pragma unroll
  for (int i=0;i<8;i++){ float r; h[i] = bf_hi(f[i], r); l[i] = bf_rne(r); }
  hv.x = (int)((unsigned)h[0] | ((unsigned)h[1]<<16));
  hv.y = (int)((unsigned)h[2] | ((unsigned)h[3]<<16));
  hv.z = (int)((unsigned)h[4] | ((unsigned)h[5]<<16));
  hv.w = (int)((unsigned)h[6] | ((unsigned)h[7]<<16));
  lv.x = (int)((unsigned)l[0] | ((unsigned)l[1]<<16));
  lv.y = (int)((unsigned)l[2] | ((unsigned)l[3]<<16));
  lv.z = (int)((unsigned)l[4] | ((unsigned)l[5]<<16));
  lv.w = (int)((unsigned)l[6] | ((unsigned)l[7]<<16));
}

// ---------------- edge dtype detect + CSR build ----------------

__global__ void k_detect(const int* __restrict__ ei, int* __restrict__ flag){
  int t = threadIdx.x;
  unsigned long long b = __ballot(ei[2*t+1] == 0);
  if (t == 0) flag[0] = (b == ~0ull) ? 1 : 0;
}

__global__ void k_zero(int* __restrict__ p, int n){
  int i = blockIdx.x*256 + threadIdx.x;
  if (i < n) p[i] = 0;
}

__global__ void k_deg(const int* __restrict__ ei, const int* __restrict__ flag, int* __restrict__ deg){
  int e = blockIdx.x*256 + threadIdx.x;
  if (e >= NEDGE) return;
  int d = flag[0] ? ei[2*(NEDGE+e)] : ei[NEDGE+e];
  atomicAdd(&deg[d], 1);
}

__global__ void k_scan1(const int* __restrict__ deg, int* __restrict__ rp, int* __restrict__ bsums){
  __shared__ int sd[256];
  int t = threadIdx.x, base = blockIdx.x*1024 + t*4;
  int v0=0,v1=0,v2=0,v3=0;
  if (base+3 < N_NODES){ int4 q = *(const int4*)(deg+base); v0=q.x; v1=q.y; v2=q.z; v3=q.w; }
  else {
    if (base   < N_NODES) v0 = deg[base];
    if (base+1 < N_NODES) v1 = deg[base+1];
    if (base+2 < N_NODES) v2 = deg[base+2];
    if (base+3 < N_NODES) v3 = deg[base+3];
  }
  int s = v0+v1+v2+v3;
  sd[t] = s; __syncthreads();
  #pragma unroll
  for (int o=1;o<256;o<<=1){
    int x = (t>=o) ? sd[t-o] : 0;
    __syncthreads();
    sd[t] += x;
    __syncthreads();
  }
  int excl = sd[t]-s;
  if (base   < N_NODES) rp[base  ] = excl;
  if (base+1 < N_NODES) rp[base+1] = excl+v0;
  if (base+2 < N_NODES) rp[base+2] = excl+v0+v1;
  if (base+3 < N_NODES) rp[base+3] = excl+v0+v1+v2;
  if (t==255) bsums[blockIdx.x] = sd[255];
}

__global__ void k_scan2(int* __restrict__ bsums, int nb){
  if (threadIdx.x==0 && blockIdx.x==0){
    int run = 0;
    for (int i=0;i<nb;i++){ int x = bsums[i]; bsums[i] = run; run += x; }
  }
}

__global__ void k_scan3(int* __restrict__ rp, int* __restrict__ cur, float* __restrict__ idg,
                        const int* __restrict__ deg, const int* __restrict__ bsums){
  int i = blockIdx.x*256 + threadIdx.x;
  if (i < N_NODES){
    int r = rp[i] + bsums[i>>10];
    rp[i] = r; cur[i] = r;
    int d = deg[i];
    idg[i] = (d>0) ? 1.0f/(float)d : 0.0f;
  } else if (i == N_NODES){
    rp[N_NODES] = NEDGE;
  }
}

__global__ void k_fill(const int* __restrict__ ei, const int* __restrict__ flag,
                       int* __restrict__ cur, int* __restrict__ col){
  int e = blockIdx.x*256 + threadIdx.x;
  if (e >= NEDGE) return;
  int s,d;
  if (flag[0]){ s = ei[2*e]; d = ei[2*(NEDGE+e)]; }
  else        { s = ei[e];   d = ei[NEDGE+e];   }
  int pos = atomicAdd(&cur[d], 1);
  col[pos] = s;
}

// ---------------- weight prepack into MFMA fragment chunks ----------------
// conv wp: chunk = (((l*9+k)*4+cb)*8+ob)*2 + plane; chunk payload = 512 ushorts:
//   lane (64) x 8 bf16: value w[k][c = cb*32+(lane>>4)*8+e][o = ob*16+(lane&15)]
// gemm wg: chunk = ((l*8+kstep)*8+ob)*2 + plane; j = kstep*32+(lane>>4)*8+e;
//   j<128 -> wl[o][j], else wr[o][j-128]
// clf cwt[c][o] fp32 (kernel unchanged)

__global__ void k_pack(const float* __restrict__ tw, const float* __restrict__ wl,
                       const float* __restrict__ wr, const float* __restrict__ cw,
                       unsigned short* __restrict__ wp, unsigned short* __restrict__ wg,
                       float* __restrict__ cwt){
  int i = blockIdx.x*256 + threadIdx.x;
  const int T1v = 442368, T2v = 98304, T3v = 8192;
  if (i < T1v){
    int e = i & 7, lane = (i>>3)&63, ob = (i>>9)&7, cb = (i>>12)&3, kl = i>>14; // kl in 0..26
    int k = kl % KW, l = kl / KW;
    int o = ob*16 + (lane&15), c = cb*32 + (lane>>4)*8 + e;
    float v = tw[(((l*128+o)*128+c)*KW) + k];
    float rem; unsigned short hi = bf_hi(v, rem); unsigned short lo = bf_rne(rem);
    int chunk = (((l*KW+k)*4+cb)*8+ob)*2;
    wp[(size_t)chunk*512 + lane*8 + e]     = hi;
    wp[(size_t)(chunk+1)*512 + lane*8 + e] = lo;
  } else if (i < T1v+T2v){
    int i2 = i - T1v;
    int e = i2 & 7, lane = (i2>>3)&63, ob = (i2>>9)&7, ks = (i2>>12)&7, l = i2>>15;
    int o = ob*16 + (lane&15), j = ks*32 + (lane>>4)*8 + e;
    float v = (j < 128) ? wl[(l*128+o)*128 + j] : wr[(l*128+o)*128 + (j-128)];
    float rem; unsigned short hi = bf_hi(v, rem); unsigned short lo = bf_rne(rem);
    int chunk = ((l*8+ks)*8+ob)*2;
    wg[(size_t)chunk*512 + lane*8 + e]     = hi;
    wg[(size_t)(chunk+1)*512 + lane*8 + e] = lo;
  } else if (i < T1v+T2v+T3v){
    int j3 = i - (T1v+T2v);
    int o = j3 & 63, c = j3 >> 6;
    cwt[j3] = cw[o*128 + c];
  }
}

// ---------------- conv via MFMA ----------------
// block: 128 nodes x 128 outs, 256 threads = 4 waves; wave w -> cols [w*32, w*32+32)
// K = 9 taps x 128 ch, processed as two 64-ch halves staged in LDS (hi/lo bf16).
// LDS plane: [136 rows][64 ushorts], 16B chunks XOR-swizzled by (row&7).

#define CROWS 136

__global__ __launch_bounds__(256, 2) void k_convm(const float* __restrict__ xin,
                                                  const unsigned short* __restrict__ wpl,
                                                  const float* __restrict__ tb,
                                                  float* __restrict__ hout){
  __shared__ unsigned short sh[2*CROWS*64];     // hi plane, lo plane (34816 B)
  const int t = threadIdx.x;
  const int n0 = blockIdx.x*128;
  const int l = t & 63, w = t >> 6;
  const int l15 = l & 15, kg = l >> 4;
  const bf16x8* Bp = (const bf16x8*)wpl;

  f32x4 acc[8][2];
  #pragma unroll
  for (int rf=0;rf<8;rf++){ acc[rf][0] = (f32x4)0.f; acc[rf][1] = (f32x4)0.f; }

  // B prefetch for first K-step (k=0, cbg=0)
  bf16x8 B00, B01, B10, B11;
  {
    int ch = ((0*4+0)*8 + 2*w)*2;
    B00 = Bp[ch*64 + l]; B01 = Bp[(ch+1)*64 + l];
    B10 = Bp[(ch+2)*64 + l]; B11 = Bp[(ch+3)*64 + l];
  }

  for (int half = 0; half < 2; ++half){
    if (half) __syncthreads();     // all reads of previous half done
    // stage: rows [0,136) -> nodes n0-4+row, channels [half*64, half*64+64)
    for (int u = t; u < CROWS*8; u += 256){
      int row = u >> 3, c8 = u & 7;
      int gn = n0 - PADW + row;
      float4 f0 = make_float4(0.f,0.f,0.f,0.f), f1 = f0;
      if (gn >= 0 && gn < N_NODES){
        const float* src = xin + (size_t)gn*FDIM + half*64 + c8*8;
        f0 = *(const float4*)src; f1 = *(const float4*)(src+4);
      }
      int4 hv, lv; cvt8(f0, f1, hv, lv);
      int idx = row*64 + ((c8 ^ (row&7)) << 3);
      *(int4*)&sh[idx] = hv;
      *(int4*)&sh[CROWS*64 + idx] = lv;
    }
    __syncthreads();

    for (int kk = 0; kk < 18; ++kk){
      int k = kk >> 1, cb2 = kk & 1;
      bf16x8 Bc00=B00, Bc01=B01, Bc10=B10, Bc11=B11;
      // prefetch next K-step's B
      {
        int it = half*18 + kk;
        int itn = (it+1 < 36) ? it+1 : it;
        int halfn = itn/18, kkn = itn%18;
        int kn = kkn>>1, cb2n = kkn&1, cbgn = halfn*2 + cb2n;
        int ch = ((kn*4+cbgn)*8 + 2*w)*2;
        B00 = Bp[ch*64 + l]; B01 = Bp[(ch+1)*64 + l];
        B10 = Bp[(ch+2)*64 + l]; B11 = Bp[(ch+3)*64 + l];
      }
      int cc3 = cb2*4 + kg;                      // chunk within 64-ch half
      int swz = ((cc3 ^ ((l15 + k) & 7)) << 3);  // row&7 == (l15+k)&7 (rf*16 ≡ 0 mod 8)
      int base = (l15 + k)*64 + swz;
      #pragma unroll
      for (int rf = 0; rf < 8; ++rf){
        int idx = base + rf*16*64;
        bf16x8 Ah = *(const bf16x8*)&sh[idx];
        bf16x8 Al = *(const bf16x8*)&sh[CROWS*64 + idx];
        acc[rf][0] = __builtin_amdgcn_mfma_f32_16x16x32_bf16(Ah, Bc00, acc[rf][0], 0,0,0);
        acc[rf][0] = __builtin_amdgcn_mfma_f32_16x16x32_bf16(Ah, Bc01, acc[rf][0], 0,0,0);
        acc[rf][0] = __builtin_amdgcn_mfma_f32_16x16x32_bf16(Al, Bc00, acc[rf][0], 0,0,0);
        acc[rf][1] = __builtin_amdgcn_mfma_f32_16x16x32_bf16(Ah, Bc10, acc[rf][1], 0,0,0);
        acc[rf][1] = __builtin_amdgcn_mfma_f32_16x16x32_bf16(Ah, Bc11, acc[rf][1], 0,0,0);
        acc[rf][1] = __builtin_amdgcn_mfma_f32_16x16x32_bf16(Al, Bc10, acc[rf][1], 0,0,0);
      }
    }
  }

  // epilogue: bias + relu; D row = (lane>>4)*4 + reg, col = lane&15
  int o0 = w*32 + l15, o1 = o0 + 16;
  float tb0 = tb[o0], tb1 = tb[o1];
  #pragma unroll
  for (int rf = 0; rf < 8; ++rf){
    #pragma unroll
    for (int j = 0; j < 4; ++j){
      int n = n0 + rf*16 + kg*4 + j;
      if (n < N_NODES){
        hout[(size_t)n*FDIM + o0] = relu_(acc[rf][0][j] + tb0);
        hout[(size_t)n*FDIM + o1] = relu_(acc[rf][1][j] + tb1);
      }
    }
  }
}

// ---------------- SAGE mean aggregation (CSR gather) ----------------

__global__ __launch_bounds__(256) void k_agg(const float* __restrict__ h, const int* __restrict__ rp,
                                             const int* __restrict__ col, const float* __restrict__ idg,
                                             float* __restrict__ agg){
  int n = blockIdx.x*4 + (threadIdx.x>>6);
  int lane = threadIdx.x & 63;
  if (n >= N_NODES) return;
  int s0 = rp[n], s1 = rp[n+1];
  float ax = 0.f, ay = 0.f;
  for (int e=s0;e<s1;e++){
    int s = col[e];
    float2 v = *(const float2*)(h + (size_t)s*FDIM + lane*2);
    ax += v.x; ay += v.y;
  }
  float wv = idg[n];
  float2 r; r.x = ax*wv; r.y = ay*wv;
  *(float2*)(agg + (size_t)n*FDIM + lane*2) = r;
}

// ---------------- SAGE linear + BN + ReLU via MFMA ----------------
// K = 256: phases p=0..3 -> (src = p>>1 ? h : agg, channel half = p&1), kstep = p*2+cb2.

__global__ __launch_bounds__(256, 2) void k_gemmm(const float* __restrict__ aggv,
                                                  const float* __restrict__ hv,
                                                  const unsigned short* __restrict__ wgl,
                                                  const float* __restrict__ bl,
                                                  const float* __restrict__ bng, const float* __restrict__ bnb,
                                                  const float* __restrict__ bnm, const float* __restrict__ bnv,
                                                  float* __restrict__ xout){
  __shared__ unsigned short sh[2*128*64];       // 32768 B
  const int t = threadIdx.x;
  const int n0 = blockIdx.x*128;
  const int l = t & 63, w = t >> 6;
  const int l15 = l & 15, kg = l >> 4;
  const bf16x8* Bp = (const bf16x8*)wgl;

  f32x4 acc[8][2];
  #pragma unroll
  for (int rf=0;rf<8;rf++){ acc[rf][0] = (f32x4)0.f; acc[rf][1] = (f32x4)0.f; }

  bf16x8 B00, B01, B10, B11;
  {
    int ch = (0*8 + 2*w)*2;
    B00 = Bp[ch*64 + l]; B01 = Bp[(ch+1)*64 + l];
    B10 = Bp[(ch+2)*64 + l]; B11 = Bp[(ch+3)*64 + l];
  }

  for (int p = 0; p < 4; ++p){
    if (p) __syncthreads();
    const float* src = (p >= 2) ? hv : aggv;
    int ch0 = (p & 1)*64;
    for (int u = t; u < 128*8; u += 256){
      int row = u >> 3, c8 = u & 7;
      int gn = n0 + row;
      float4 f0 = make_float4(0.f,0.f,0.f,0.f), f1 = f0;
      if (gn < N_NODES){
        const float* sp = src + (size_t)gn*FDIM + ch0 + c8*8;
        f0 = *(const float4*)sp; f1 = *(const float4*)(sp+4);
      }
      int4 hvv, lvv; cvt8(f0, f1, hvv, lvv);
      int idx = row*64 + ((c8 ^ (row&7)) << 3);
      *(int4*)&sh[idx] = hvv;
      *(int4*)&sh[128*64 + idx] = lvv;
    }
    __syncthreads();

    for (int cb2 = 0; cb2 < 2; ++cb2){
      bf16x8 Bc00=B00, Bc01=B01, Bc10=B10, Bc11=B11;
      {
        int ks = p*2 + cb2;
        int ksn = (ks+1 < 8) ? ks+1 : ks;
        int ch = (ksn*8 + 2*w)*2;
        B00 = Bp[ch*64 + l]; B01 = Bp[(ch+1)*64 + l];
        B10 = Bp[(ch+2)*64 + l]; B11 = Bp[(ch+3)*64 + l];
      }
      int cc3 = cb2*4 + kg;
      int swz = ((cc3 ^ (l15 & 7)) << 3);
      int base = l15*64 + swz;
      #pragma unroll
      for (int rf = 0; rf < 8; ++rf){
        int idx = base + rf*16*64;
        bf16x8 Ah = *(const bf16x8*)&sh[idx];
        bf16x8 Al = *(const bf16x8*)&sh[128*64 + idx];
        acc[rf][0] = __builtin_amdgcn_mfma_f32_16x16x32_bf16(Ah, Bc00, acc[rf][0], 0,0,0);
        acc[rf][0] = __builtin_amdgcn_mfma_f32_16x16x32_bf16(Ah, Bc01, acc[rf][0], 0,0,0);
        acc[rf][0] = __builtin_amdgcn_mfma_f32_16x16x32_bf16(Al, Bc00, acc[rf][0], 0,0,0);
        acc[rf][1] = __builtin_amdgcn_mfma_f32_16x16x32_bf16(Ah, Bc10, acc[rf][1], 0,0,0);
        acc[rf][1] = __builtin_amdgcn_mfma_f32_16x16x32_bf16(Ah, Bc11, acc[rf][1], 0,0,0);
        acc[rf][1] = __builtin_amdgcn_mfma_f32_16x16x32_bf16(Al, Bc10, acc[rf][1], 0,0,0);
      }
    }
  }

  // epilogue: out = s*acc + (s*(bl-m)+b), relu
  int o0 = w*32 + l15, o1 = o0 + 16;
  float s0 = bng[o0]*rsqrtf(bnv[o0]+BN_EPS);
  float c0 = bnb[o0] + s0*(bl[o0]-bnm[o0]);
  float s1 = bng[o1]*rsqrtf(bnv[o1]+BN_EPS);
  float c1 = bnb[o1] + s1*(bl[o1]-bnm[o1]);
  #pragma unroll
  for (int rf = 0; rf < 8; ++rf){
    #pragma unroll
    for (int j = 0; j < 4; ++j){
      int n = n0 + rf*16 + kg*4 + j;
      if (n < N_NODES){
        xout[(size_t)n*FDIM + o0] = relu_(s0*acc[rf][0][j] + c0);
        xout[(size_t)n*FDIM + o1] = relu_(s1*acc[rf][1][j] + c1);
      }
    }
  }
}

// ---------------- classifier + log_softmax (fp32, unchanged) ----------------

template<int ST>
__device__ __forceinline__ void stage64(float (*As)[ST], const float* __restrict__ src, int n0, int t){
  for (int u=t; u<64*32; u+=256){
    int row = u>>5, c4 = (u&31)*4;
    int gn = n0 + row;
    float4 v = make_float4(0.f,0.f,0.f,0.f);
    if (gn < N_NODES) v = *(const float4*)(src + (size_t)gn*FDIM + c4);
    As[c4  ][row] = v.x; As[c4+1][row] = v.y; As[c4+2][row] = v.z; As[c4+3][row] = v.w;
  }
}

__global__ __launch_bounds__(256) void k_clf(const float* __restrict__ x, const float* __restrict__ cwt,
                                             const float* __restrict__ cb, float* __restrict__ out){
  __shared__ float As[128][68];
  __shared__ float mxl[64];
  const int t = threadIdx.x, n0 = blockIdx.x*64;
  const int ng = t & 15, og = t>>4;
  float acc[4][4];
  #pragma unroll
  for (int i=0;i<4;i++)
    #pragma unroll
    for (int j=0;j<4;j++) acc[i][j] = 0.f;

  stage64<68>(As, x, n0, t);
  __syncthreads();
  #pragma unroll 2
  for (int c=0;c<128;c++){
    float aa[4] = {As[c][ng], As[c][ng+16], As[c][ng+32], As[c][ng+48]};
    float4 b = *(const float4*)(cwt + c*64 + og*4);
    float bb[4] = {b.x,b.y,b.z,b.w};
    #pragma unroll
    for (int i=0;i<4;i++)
      #pragma unroll
      for (int j=0;j<4;j++) acc[i][j] = fmaf(aa[i], bb[j], acc[i][j]);
  }
  __syncthreads();
  float4 cb4 = *(const float4*)(cb + og*4);
  float cbv[4] = {cb4.x,cb4.y,cb4.z,cb4.w};
  #pragma unroll
  for (int i=0;i<4;i++)
    #pragma unroll
    for (int j=0;j<4;j++) As[ng+16*i][og*4+j] = acc[i][j] + cbv[j];
  __syncthreads();
  if (t < 64){
    float mx = -1e30f;
    #pragma unroll 8
    for (int o=0;o<64;o++) mx = fmaxf(mx, As[t][o]);
    float se = 0.f;
    #pragma unroll 8
    for (int o=0;o<64;o++) se += expf(As[t][o]-mx);
    mxl[t] = mx + logf(se);
  }
  __syncthreads();
  #pragma unroll
  for (int v=0;v<4;v++){
    int q = t + v*256;
    int r = q>>4, o4 = (q&15)*4;
    int n = n0 + r;
    if (n < N_NODES){
      float4 L = *(const float4*)&As[r][o4];
      float m = mxl[r];
      float4 wv; wv.x = L.x-m; wv.y = L.y-m; wv.z = L.z-m; wv.w = L.w-m;
      *(float4*)(out + (size_t)n*OUTC + o4) = wv;
    }
  }
}

// ---------------- launch ----------------

extern "C" void kernel_launch(void* const* d_in, const int* in_sizes, int n_in,
                              void* d_out, int out_size, void* d_ws, size_t ws_size,
                              hipStream_t stream) {
  const float* x   = (const float*)d_in[0];
  const int*   ei  = (const int*)  d_in[1];
  const float* tw  = (const float*)d_in[2];
  const float* tb  = (const float*)d_in[3];
  const float* wl  = (const float*)d_in[4];
  const float* bl  = (const float*)d_in[5];
  const float* wr  = (const float*)d_in[6];
  const float* bng = (const float*)d_in[7];
  const float* bnb = (const float*)d_in[8];
  const float* bnm = (const float*)d_in[9];
  const float* bnv = (const float*)d_in[10];
  const float* cw  = (const float*)d_in[11];
  const float* cb  = (const float*)d_in[12];
  float* out = (float*)d_out;
  char* ws = (char*)d_ws;

  auto align256 = [](size_t v){ return (v + 255) & ~(size_t)255; };
  size_t off = 0;
  auto take = [&](size_t bytes){ size_t o = off; off += align256(bytes); return o; };
  float* xbuf  = (float*)(ws + take((size_t)N_NODES*FDIM*4));
  float* hbuf  = (float*)(ws + take((size_t)N_NODES*FDIM*4));
  float* aggb  = (float*)(ws + take((size_t)N_NODES*FDIM*4));
  unsigned short* wp = (unsigned short*)(ws + take((size_t)884736*2));  // conv frags
  unsigned short* wg = (unsigned short*)(ws + take((size_t)196608*2));  // gemm frags
  float* cwt   = (float*)(ws + take((size_t)128*64*4));
  int*   deg   = (int*)  (ws + take((size_t)N_NODES*4));
  int*   rp    = (int*)  (ws + take((size_t)(N_NODES+1)*4));
  int*   cur   = (int*)  (ws + take((size_t)N_NODES*4));
  int*   col   = (int*)  (ws + take((size_t)NEDGE*4));
  float* idg   = (float*)(ws + take((size_t)N_NODES*4));
  int*   bsums = (int*)  (ws + take(256));
  int*   flag  = (int*)  (ws + take(256));
  (void)ws_size; (void)in_sizes; (void)n_in; (void)out_size;

  const int NB_N   = (N_NODES + 255)/256;
  const int NB_E   = (NEDGE   + 255)/256;
  const int NB_SC  = (N_NODES + 1023)/1024;
  const int NB_T64 = (N_NODES + 63)/64;     // 782 (clf)
  const int NB_T128= (N_NODES + 127)/128;   // 391 (conv/gemm)
  const int NB_PK  = (442368 + 98304 + 8192)/256; // 2144

  k_detect<<<1, 64, 0, stream>>>(ei, flag);
  k_zero  <<<NB_N, 256, 0, stream>>>(deg, N_NODES);
  k_deg   <<<NB_E, 256, 0, stream>>>(ei, flag, deg);
  k_scan1 <<<NB_SC, 256, 0, stream>>>(deg, rp, bsums);
  k_scan2 <<<1, 64, 0, stream>>>(bsums, NB_SC);
  k_scan3 <<<NB_N+1, 256, 0, stream>>>(rp, cur, idg, deg, bsums);
  k_fill  <<<NB_E, 256, 0, stream>>>(ei, flag, cur, col);
  k_pack  <<<NB_PK, 256, 0, stream>>>(tw, wl, wr, cw, wp, wg, cwt);

  for (int l=0; l<NLAYER; l++){
    const float* xin = (l==0) ? x : xbuf;
    k_convm<<<NB_T128, 256, 0, stream>>>(xin, wp + (size_t)l*294912, tb + l*128, hbuf);
    k_agg  <<<N_NODES/4, 256, 0, stream>>>(hbuf, rp, col, idg, aggb);
    k_gemmm<<<NB_T128, 256, 0, stream>>>(aggb, hbuf, wg + (size_t)l*65536,
                                         bl + l*128, bng + l*128, bnb + l*128,
                                         bnm + l*128, bnv + l*128, xbuf);
  }
  k_clf<<<NB_T64, 256, 0, stream>>>(xbuf, cwt, cb, out);
}

// Round 11
// 490.686 us; speedup vs baseline: 2.9680x; 1.2360x over previous
//
#include <hip/hip_runtime.h>
#include <cstddef>
#include <cstdint>

// STGCN v3: all intermediate activations stored as bf16 hi/lo planes.
//   - k_agg gathers ONLY the hi plane (256B/row, half of v2's 512B) with
//     2-edge-per-wave ILP; accumulates fp32; writes agg hi/lo planes.
//   - MFMA staging (gemm all phases, conv layers 1-2) loads planes directly:
//     no cvt8 in the staging loops. Conv layer 0 keeps the fp32->hi/lo path.
//   - k_clf reconstructs fp32 = f(hi)+f(lo).
// MFMA inner loops identical to v2 (measured-good: total 606us, agg was 34%).

#define N_NODES 50000
#define FDIM    128
#define OUTC    64
#define NLAYER  3
#define KW      9
#define PADW    4
#define NEDGE   600000
#define BN_EPS  1e-5f

typedef short bf16x8 __attribute__((ext_vector_type(8)));
typedef float f32x4  __attribute__((ext_vector_type(4)));

__device__ __forceinline__ float relu_(float v){ return v > 0.f ? v : 0.f; }

__device__ __forceinline__ unsigned short bf_rne(float x){
  unsigned u = __float_as_uint(x);
  unsigned r = u + 0x7fff + ((u >> 16) & 1);
  return (unsigned short)(r >> 16);
}
__device__ __forceinline__ unsigned short bf_hi(float x, float& rem){
  unsigned short h = bf_rne(x);
  rem = x - __uint_as_float(((unsigned)h) << 16);
  return h;
}
__device__ __forceinline__ float bf2f(unsigned short u){
  return __uint_as_float(((unsigned)u) << 16);
}
// convert 8 floats -> packed hi int4 + lo int4 (layer-0 conv staging only)
__device__ __forceinline__ void cvt8(const float4& f0, const float4& f1, int4& hv, int4& lv){
  float f[8] = {f0.x,f0.y,f0.z,f0.w,f1.x,f1.y,f1.z,f1.w};
  unsigned short h[8], l[8];
  #pragma unroll
  for (int i=0;i<8;i++){ float r; h[i] = bf_hi(f[i], r); l[i] = bf_rne(r); }
  hv.x = (int)((unsigned)h[0] | ((unsigned)h[1]<<16));
  hv.y = (int)((unsigned)h[2] | ((unsigned)h[3]<<16));
  hv.z = (int)((unsigned)h[4] | ((unsigned)h[5]<<16));
  hv.w = (int)((unsigned)h[6] | ((unsigned)h[7]<<16));
  lv.x = (int)((unsigned)l[0] | ((unsigned)l[1]<<16));
  lv.y = (int)((unsigned)l[2] | ((unsigned)l[3]<<16));
  lv.z = (int)((unsigned)l[4] | ((unsigned)l[5]<<16));
  lv.w = (int)((unsigned)l[6] | ((unsigned)l[7]<<16));
}

// ---------------- edge dtype detect + CSR build ----------------

__global__ void k_detect(const int* __restrict__ ei, int* __restrict__ flag){
  int t = threadIdx.x;
  unsigned long long b = __ballot(ei[2*t+1] == 0);
  if (t == 0) flag[0] = (b == ~0ull) ? 1 : 0;
}

__global__ void k_zero(int* __restrict__ p, int n){
  int i = blockIdx.x*256 + threadIdx.x;
  if (i < n) p[i] = 0;
}

__global__ void k_deg(const int* __restrict__ ei, const int* __restrict__ flag, int* __restrict__ deg){
  int e = blockIdx.x*256 + threadIdx.x;
  if (e >= NEDGE) return;
  int d = flag[0] ? ei[2*(NEDGE+e)] : ei[NEDGE+e];
  atomicAdd(&deg[d], 1);
}

__global__ void k_scan1(const int* __restrict__ deg, int* __restrict__ rp, int* __restrict__ bsums){
  __shared__ int sd[256];
  int t = threadIdx.x, base = blockIdx.x*1024 + t*4;
  int v0=0,v1=0,v2=0,v3=0;
  if (base+3 < N_NODES){ int4 q = *(const int4*)(deg+base); v0=q.x; v1=q.y; v2=q.z; v3=q.w; }
  else {
    if (base   < N_NODES) v0 = deg[base];
    if (base+1 < N_NODES) v1 = deg[base+1];
    if (base+2 < N_NODES) v2 = deg[base+2];
    if (base+3 < N_NODES) v3 = deg[base+3];
  }
  int s = v0+v1+v2+v3;
  sd[t] = s; __syncthreads();
  #pragma unroll
  for (int o=1;o<256;o<<=1){
    int x = (t>=o) ? sd[t-o] : 0;
    __syncthreads();
    sd[t] += x;
    __syncthreads();
  }
  int excl = sd[t]-s;
  if (base   < N_NODES) rp[base  ] = excl;
  if (base+1 < N_NODES) rp[base+1] = excl+v0;
  if (base+2 < N_NODES) rp[base+2] = excl+v0+v1;
  if (base+3 < N_NODES) rp[base+3] = excl+v0+v1+v2;
  if (t==255) bsums[blockIdx.x] = sd[255];
}

__global__ void k_scan2(int* __restrict__ bsums, int nb){
  if (threadIdx.x==0 && blockIdx.x==0){
    int run = 0;
    for (int i=0;i<nb;i++){ int x = bsums[i]; bsums[i] = run; run += x; }
  }
}

__global__ void k_scan3(int* __restrict__ rp, int* __restrict__ cur, float* __restrict__ idg,
                        const int* __restrict__ deg, const int* __restrict__ bsums){
  int i = blockIdx.x*256 + threadIdx.x;
  if (i < N_NODES){
    int r = rp[i] + bsums[i>>10];
    rp[i] = r; cur[i] = r;
    int d = deg[i];
    idg[i] = (d>0) ? 1.0f/(float)d : 0.0f;
  } else if (i == N_NODES){
    rp[N_NODES] = NEDGE;
  }
}

__global__ void k_fill(const int* __restrict__ ei, const int* __restrict__ flag,
                       int* __restrict__ cur, int* __restrict__ col){
  int e = blockIdx.x*256 + threadIdx.x;
  if (e >= NEDGE) return;
  int s,d;
  if (flag[0]){ s = ei[2*e]; d = ei[2*(NEDGE+e)]; }
  else        { s = ei[e];   d = ei[NEDGE+e];   }
  int pos = atomicAdd(&cur[d], 1);
  col[pos] = s;
}

// ---------------- weight prepack into MFMA fragment chunks (as v2) ----------------

__global__ void k_pack(const float* __restrict__ tw, const float* __restrict__ wl,
                       const float* __restrict__ wr, const float* __restrict__ cw,
                       unsigned short* __restrict__ wp, unsigned short* __restrict__ wg,
                       float* __restrict__ cwt){
  int i = blockIdx.x*256 + threadIdx.x;
  const int T1v = 442368, T2v = 98304, T3v = 8192;
  if (i < T1v){
    int e = i & 7, lane = (i>>3)&63, ob = (i>>9)&7, cb = (i>>12)&3, kl = i>>14;
    int k = kl % KW, l = kl / KW;
    int o = ob*16 + (lane&15), c = cb*32 + (lane>>4)*8 + e;
    float v = tw[(((l*128+o)*128+c)*KW) + k];
    float rem; unsigned short hi = bf_hi(v, rem); unsigned short lo = bf_rne(rem);
    int chunk = (((l*KW+k)*4+cb)*8+ob)*2;
    wp[(size_t)chunk*512 + lane*8 + e]     = hi;
    wp[(size_t)(chunk+1)*512 + lane*8 + e] = lo;
  } else if (i < T1v+T2v){
    int i2 = i - T1v;
    int e = i2 & 7, lane = (i2>>3)&63, ob = (i2>>9)&7, ks = (i2>>12)&7, l = i2>>15;
    int o = ob*16 + (lane&15), j = ks*32 + (lane>>4)*8 + e;
    float v = (j < 128) ? wl[(l*128+o)*128 + j] : wr[(l*128+o)*128 + (j-128)];
    float rem; unsigned short hi = bf_hi(v, rem); unsigned short lo = bf_rne(rem);
    int chunk = ((l*8+ks)*8+ob)*2;
    wg[(size_t)chunk*512 + lane*8 + e]     = hi;
    wg[(size_t)(chunk+1)*512 + lane*8 + e] = lo;
  } else if (i < T1v+T2v+T3v){
    int j3 = i - (T1v+T2v);
    int o = j3 & 63, c = j3 >> 6;
    cwt[j3] = cw[o*128 + c];
  }
}

// ---------------- conv via MFMA (v2 loop; staging/epilogue on planes) ----------------

#define CROWS 136

__global__ __launch_bounds__(256, 2) void k_convm(const float* __restrict__ xf,
                                                  const unsigned short* __restrict__ xhi,
                                                  const unsigned short* __restrict__ xlo,
                                                  const int use_planes,
                                                  const unsigned short* __restrict__ wpl,
                                                  const float* __restrict__ tb,
                                                  unsigned short* __restrict__ hhi,
                                                  unsigned short* __restrict__ hlo){
  __shared__ unsigned short sh[2*CROWS*64];
  const int t = threadIdx.x;
  const int n0 = blockIdx.x*128;
  const int l = t & 63, w = t >> 6;
  const int l15 = l & 15, kg = l >> 4;
  const bf16x8* Bp = (const bf16x8*)wpl;

  f32x4 acc[8][2];
  #pragma unroll
  for (int rf=0;rf<8;rf++){ acc[rf][0] = (f32x4)0.f; acc[rf][1] = (f32x4)0.f; }

  bf16x8 B00, B01, B10, B11;
  {
    int ch = ((0*4+0)*8 + 2*w)*2;
    B00 = Bp[ch*64 + l]; B01 = Bp[(ch+1)*64 + l];
    B10 = Bp[(ch+2)*64 + l]; B11 = Bp[(ch+3)*64 + l];
  }

  for (int half = 0; half < 2; ++half){
    if (half) __syncthreads();
    for (int u = t; u < CROWS*8; u += 256){
      int row = u >> 3, c8 = u & 7;
      int gn = n0 - PADW + row;
      int4 hv = make_int4(0,0,0,0), lv = make_int4(0,0,0,0);
      if (gn >= 0 && gn < N_NODES){
        if (use_planes){
          size_t o = (size_t)gn*FDIM + half*64 + c8*8;
          hv = *(const int4*)(xhi + o);
          lv = *(const int4*)(xlo + o);
        } else {
          const float* src = xf + (size_t)gn*FDIM + half*64 + c8*8;
          float4 f0 = *(const float4*)src, f1 = *(const float4*)(src+4);
          cvt8(f0, f1, hv, lv);
        }
      }
      int idx = row*64 + ((c8 ^ (row&7)) << 3);
      *(int4*)&sh[idx] = hv;
      *(int4*)&sh[CROWS*64 + idx] = lv;
    }
    __syncthreads();

    for (int kk = 0; kk < 18; ++kk){
      int k = kk >> 1, cb2 = kk & 1;
      bf16x8 Bc00=B00, Bc01=B01, Bc10=B10, Bc11=B11;
      {
        int it = half*18 + kk;
        int itn = (it+1 < 36) ? it+1 : it;
        int halfn = itn/18, kkn = itn%18;
        int kn = kkn>>1, cb2n = kkn&1, cbgn = halfn*2 + cb2n;
        int ch = ((kn*4+cbgn)*8 + 2*w)*2;
        B00 = Bp[ch*64 + l]; B01 = Bp[(ch+1)*64 + l];
        B10 = Bp[(ch+2)*64 + l]; B11 = Bp[(ch+3)*64 + l];
      }
      int cc3 = cb2*4 + kg;
      int swz = ((cc3 ^ ((l15 + k) & 7)) << 3);
      int base = (l15 + k)*64 + swz;
      #pragma unroll
      for (int rf = 0; rf < 8; ++rf){
        int idx = base + rf*16*64;
        bf16x8 Ah = *(const bf16x8*)&sh[idx];
        bf16x8 Al = *(const bf16x8*)&sh[CROWS*64 + idx];
        acc[rf][0] = __builtin_amdgcn_mfma_f32_16x16x32_bf16(Ah, Bc00, acc[rf][0], 0,0,0);
        acc[rf][0] = __builtin_amdgcn_mfma_f32_16x16x32_bf16(Ah, Bc01, acc[rf][0], 0,0,0);
        acc[rf][0] = __builtin_amdgcn_mfma_f32_16x16x32_bf16(Al, Bc00, acc[rf][0], 0,0,0);
        acc[rf][1] = __builtin_amdgcn_mfma_f32_16x16x32_bf16(Ah, Bc10, acc[rf][1], 0,0,0);
        acc[rf][1] = __builtin_amdgcn_mfma_f32_16x16x32_bf16(Ah, Bc11, acc[rf][1], 0,0,0);
        acc[rf][1] = __builtin_amdgcn_mfma_f32_16x16x32_bf16(Al, Bc10, acc[rf][1], 0,0,0);
      }
    }
  }

  int o0 = w*32 + l15, o1 = o0 + 16;
  float tb0 = tb[o0], tb1 = tb[o1];
  #pragma unroll
  for (int rf = 0; rf < 8; ++rf){
    #pragma unroll
    for (int j = 0; j < 4; ++j){
      int n = n0 + rf*16 + kg*4 + j;
      if (n < N_NODES){
        float v0 = relu_(acc[rf][0][j] + tb0);
        float v1 = relu_(acc[rf][1][j] + tb1);
        float r0, r1;
        unsigned short h0 = bf_hi(v0, r0), h1 = bf_hi(v1, r1);
        size_t b = (size_t)n*FDIM;
        hhi[b+o0] = h0; hlo[b+o0] = bf_rne(r0);
        hhi[b+o1] = h1; hlo[b+o1] = bf_rne(r1);
      }
    }
  }
}

// ---------------- SAGE mean aggregation: bf16-hi gather ----------------
// wave per node; half-waves process alternating edges (2 rows in flight),
// e-loop unrolled x2 (4 rows in flight). 8B/lane x 32 lanes = 256B row.

__global__ __launch_bounds__(256) void k_agg(const unsigned short* __restrict__ hhi,
                                             const int* __restrict__ rp,
                                             const int* __restrict__ col,
                                             const float* __restrict__ idg,
                                             unsigned short* __restrict__ ahi,
                                             unsigned short* __restrict__ alo){
  int n = blockIdx.x*4 + (threadIdx.x>>6);
  int lane = threadIdx.x & 63;
  int half = lane >> 5, li = lane & 31;
  if (n >= N_NODES) return;
  int s0 = rp[n], s1 = rp[n+1];
  float a0=0.f, a1=0.f, a2=0.f, a3=0.f;
  int e = s0 + half;
  for (; e + 2 < s1; e += 4){
    int sA = col[e], sB = col[e+2];
    ushort4 vA = *(const ushort4*)(hhi + (size_t)sA*FDIM + li*4);
    ushort4 vB = *(const ushort4*)(hhi + (size_t)sB*FDIM + li*4);
    a0 += bf2f(vA.x) + bf2f(vB.x);
    a1 += bf2f(vA.y) + bf2f(vB.y);
    a2 += bf2f(vA.z) + bf2f(vB.z);
    a3 += bf2f(vA.w) + bf2f(vB.w);
  }
  for (; e < s1; e += 2){
    int s = col[e];
    ushort4 v = *(const ushort4*)(hhi + (size_t)s*FDIM + li*4);
    a0 += bf2f(v.x); a1 += bf2f(v.y); a2 += bf2f(v.z); a3 += bf2f(v.w);
  }
  a0 += __shfl_xor(a0, 32);
  a1 += __shfl_xor(a1, 32);
  a2 += __shfl_xor(a2, 32);
  a3 += __shfl_xor(a3, 32);
  float wv = idg[n];
  a0 *= wv; a1 *= wv; a2 *= wv; a3 *= wv;
  float r0,r1,r2,r3;
  unsigned short h0 = bf_hi(a0,r0), h1 = bf_hi(a1,r1), h2 = bf_hi(a2,r2), h3 = bf_hi(a3,r3);
  size_t b = (size_t)n*FDIM + li*4;
  if (half == 0){
    ushort4 o; o.x=h0; o.y=h1; o.z=h2; o.w=h3;
    *(ushort4*)(ahi + b) = o;
  } else {
    ushort4 o; o.x=bf_rne(r0); o.y=bf_rne(r1); o.z=bf_rne(r2); o.w=bf_rne(r3);
    *(ushort4*)(alo + b) = o;
  }
}

// ---------------- SAGE linear + BN + ReLU via MFMA (plane staging) ----------------

__global__ __launch_bounds__(256, 2) void k_gemmm(const unsigned short* __restrict__ ahi,
                                                  const unsigned short* __restrict__ alo,
                                                  const unsigned short* __restrict__ hhi,
                                                  const unsigned short* __restrict__ hlo,
                                                  const unsigned short* __restrict__ wgl,
                                                  const float* __restrict__ bl,
                                                  const float* __restrict__ bng, const float* __restrict__ bnb,
                                                  const float* __restrict__ bnm, const float* __restrict__ bnv,
                                                  unsigned short* __restrict__ xhi,
                                                  unsigned short* __restrict__ xlo){
  __shared__ unsigned short sh[2*128*64];
  const int t = threadIdx.x;
  const int n0 = blockIdx.x*128;
  const int l = t & 63, w = t >> 6;
  const int l15 = l & 15, kg = l >> 4;
  const bf16x8* Bp = (const bf16x8*)wgl;

  f32x4 acc[8][2];
  #pragma unroll
  for (int rf=0;rf<8;rf++){ acc[rf][0] = (f32x4)0.f; acc[rf][1] = (f32x4)0.f; }

  bf16x8 B00, B01, B10, B11;
  {
    int ch = (0*8 + 2*w)*2;
    B00 = Bp[ch*64 + l]; B01 = Bp[(ch+1)*64 + l];
    B10 = Bp[(ch+2)*64 + l]; B11 = Bp[(ch+3)*64 + l];
  }

  for (int p = 0; p < 4; ++p){
    if (p) __syncthreads();
    const unsigned short* shi = (p >= 2) ? hhi : ahi;
    const unsigned short* slo = (p >= 2) ? hlo : alo;
    int ch0 = (p & 1)*64;
    for (int u = t; u < 128*8; u += 256){
      int row = u >> 3, c8 = u & 7;
      int gn = n0 + row;
      int4 hv = make_int4(0,0,0,0), lv = make_int4(0,0,0,0);
      if (gn < N_NODES){
        size_t o = (size_t)gn*FDIM + ch0 + c8*8;
        hv = *(const int4*)(shi + o);
        lv = *(const int4*)(slo + o);
      }
      int idx = row*64 + ((c8 ^ (row&7)) << 3);
      *(int4*)&sh[idx] = hv;
      *(int4*)&sh[128*64 + idx] = lv;
    }
    __syncthreads();

    for (int cb2 = 0; cb2 < 2; ++cb2){
      bf16x8 Bc00=B00, Bc01=B01, Bc10=B10, Bc11=B11;
      {
        int ks = p*2 + cb2;
        int ksn = (ks+1 < 8) ? ks+1 : ks;
        int ch = (ksn*8 + 2*w)*2;
        B00 = Bp[ch*64 + l]; B01 = Bp[(ch+1)*64 + l];
        B10 = Bp[(ch+2)*64 + l]; B11 = Bp[(ch+3)*64 + l];
      }
      int cc3 = cb2*4 + kg;
      int swz = ((cc3 ^ (l15 & 7)) << 3);
      int base = l15*64 + swz;
      #pragma unroll
      for (int rf = 0; rf < 8; ++rf){
        int idx = base + rf*16*64;
        bf16x8 Ah = *(const bf16x8*)&sh[idx];
        bf16x8 Al = *(const bf16x8*)&sh[128*64 + idx];
        acc[rf][0] = __builtin_amdgcn_mfma_f32_16x16x32_bf16(Ah, Bc00, acc[rf][0], 0,0,0);
        acc[rf][0] = __builtin_amdgcn_mfma_f32_16x16x32_bf16(Ah, Bc01, acc[rf][0], 0,0,0);
        acc[rf][0] = __builtin_amdgcn_mfma_f32_16x16x32_bf16(Al, Bc00, acc[rf][0], 0,0,0);
        acc[rf][1] = __builtin_amdgcn_mfma_f32_16x16x32_bf16(Ah, Bc10, acc[rf][1], 0,0,0);
        acc[rf][1] = __builtin_amdgcn_mfma_f32_16x16x32_bf16(Ah, Bc11, acc[rf][1], 0,0,0);
        acc[rf][1] = __builtin_amdgcn_mfma_f32_16x16x32_bf16(Al, Bc10, acc[rf][1], 0,0,0);
      }
    }
  }

  int o0 = w*32 + l15, o1 = o0 + 16;
  float s0 = bng[o0]*rsqrtf(bnv[o0]+BN_EPS);
  float c0 = bnb[o0] + s0*(bl[o0]-bnm[o0]);
  float s1 = bng[o1]*rsqrtf(bnv[o1]+BN_EPS);
  float c1 = bnb[o1] + s1*(bl[o1]-bnm[o1]);
  #pragma unroll
  for (int rf = 0; rf < 8; ++rf){
    #pragma unroll
    for (int j = 0; j < 4; ++j){
      int n = n0 + rf*16 + kg*4 + j;
      if (n < N_NODES){
        float v0 = relu_(s0*acc[rf][0][j] + c0);
        float v1 = relu_(s1*acc[rf][1][j] + c1);
        float r0, r1;
        unsigned short h0 = bf_hi(v0, r0), h1 = bf_hi(v1, r1);
        size_t b = (size_t)n*FDIM;
        xhi[b+o0] = h0; xlo[b+o0] = bf_rne(r0);
        xhi[b+o1] = h1; xlo[b+o1] = bf_rne(r1);
      }
    }
  }
}

// ---------------- classifier + log_softmax (reads hi/lo planes) ----------------

__global__ __launch_bounds__(256) void k_clf(const unsigned short* __restrict__ xhi,
                                             const unsigned short* __restrict__ xlo,
                                             const float* __restrict__ cwt,
                                             const float* __restrict__ cb, float* __restrict__ out){
  __shared__ float As[128][68];
  __shared__ float mxl[64];
  const int t = threadIdx.x, n0 = blockIdx.x*64;
  const int ng = t & 15, og = t>>4;
  float acc[4][4];
  #pragma unroll
  for (int i=0;i<4;i++)
    #pragma unroll
    for (int j=0;j<4;j++) acc[i][j] = 0.f;

  for (int u=t; u<64*16; u+=256){
    int row = u>>4, c16 = u&15;
    int gn = n0 + row;
    int4 hv = make_int4(0,0,0,0), lv = make_int4(0,0,0,0);
    if (gn < N_NODES){
      size_t o = (size_t)gn*FDIM + c16*8;
      hv = *(const int4*)(xhi + o);
      lv = *(const int4*)(xlo + o);
    }
    const unsigned short* hs = (const unsigned short*)&hv;
    const unsigned short* ls = (const unsigned short*)&lv;
    #pragma unroll
    for (int j=0;j<8;j++) As[c16*8+j][row] = bf2f(hs[j]) + bf2f(ls[j]);
  }
  __syncthreads();
  #pragma unroll 2
  for (int c=0;c<128;c++){
    float aa[4] = {As[c][ng], As[c][ng+16], As[c][ng+32], As[c][ng+48]};
    float4 b = *(const float4*)(cwt + c*64 + og*4);
    float bb[4] = {b.x,b.y,b.z,b.w};
    #pragma unroll
    for (int i=0;i<4;i++)
      #pragma unroll
      for (int j=0;j<4;j++) acc[i][j] = fmaf(aa[i], bb[j], acc[i][j]);
  }
  __syncthreads();
  float4 cb4 = *(const float4*)(cb + og*4);
  float cbv[4] = {cb4.x,cb4.y,cb4.z,cb4.w};
  #pragma unroll
  for (int i=0;i<4;i++)
    #pragma unroll
    for (int j=0;j<4;j++) As[ng+16*i][og*4+j] = acc[i][j] + cbv[j];
  __syncthreads();
  if (t < 64){
    float mx = -1e30f;
    #pragma unroll 8
    for (int o=0;o<64;o++) mx = fmaxf(mx, As[t][o]);
    float se = 0.f;
    #pragma unroll 8
    for (int o=0;o<64;o++) se += expf(As[t][o]-mx);
    mxl[t] = mx + logf(se);
  }
  __syncthreads();
  #pragma unroll
  for (int v=0;v<4;v++){
    int q = t + v*256;
    int r = q>>4, o4 = (q&15)*4;
    int n = n0 + r;
    if (n < N_NODES){
      float4 L = *(const float4*)&As[r][o4];
      float m = mxl[r];
      float4 wv; wv.x = L.x-m; wv.y = L.y-m; wv.z = L.z-m; wv.w = L.w-m;
      *(float4*)(out + (size_t)n*OUTC + o4) = wv;
    }
  }
}

// ---------------- launch ----------------

extern "C" void kernel_launch(void* const* d_in, const int* in_sizes, int n_in,
                              void* d_out, int out_size, void* d_ws, size_t ws_size,
                              hipStream_t stream) {
  const float* x   = (const float*)d_in[0];
  const int*   ei  = (const int*)  d_in[1];
  const float* tw  = (const float*)d_in[2];
  const float* tb  = (const float*)d_in[3];
  const float* wl  = (const float*)d_in[4];
  const float* bl  = (const float*)d_in[5];
  const float* wr  = (const float*)d_in[6];
  const float* bng = (const float*)d_in[7];
  const float* bnb = (const float*)d_in[8];
  const float* bnm = (const float*)d_in[9];
  const float* bnv = (const float*)d_in[10];
  const float* cw  = (const float*)d_in[11];
  const float* cb  = (const float*)d_in[12];
  float* out = (float*)d_out;
  char* ws = (char*)d_ws;

  auto align256 = [](size_t v){ return (v + 255) & ~(size_t)255; };
  size_t off = 0;
  auto take = [&](size_t bytes){ size_t o = off; off += align256(bytes); return o; };
  const size_t PLANE = (size_t)N_NODES*FDIM*2;              // 12.8 MB
  unsigned short* xhi = (unsigned short*)(ws + take(PLANE));
  unsigned short* xlo = (unsigned short*)(ws + take(PLANE));
  unsigned short* hhi = (unsigned short*)(ws + take(PLANE));
  unsigned short* hlo = (unsigned short*)(ws + take(PLANE));
  unsigned short* ahi = (unsigned short*)(ws + take(PLANE));
  unsigned short* alo = (unsigned short*)(ws + take(PLANE));
  unsigned short* wp  = (unsigned short*)(ws + take((size_t)884736*2));
  unsigned short* wg  = (unsigned short*)(ws + take((size_t)196608*2));
  float* cwt   = (float*)(ws + take((size_t)128*64*4));
  int*   deg   = (int*)  (ws + take((size_t)N_NODES*4));
  int*   rp    = (int*)  (ws + take((size_t)(N_NODES+1)*4));
  int*   cur   = (int*)  (ws + take((size_t)N_NODES*4));
  int*   col   = (int*)  (ws + take((size_t)NEDGE*4));
  float* idg   = (float*)(ws + take((size_t)N_NODES*4));
  int*   bsums = (int*)  (ws + take(256));
  int*   flag  = (int*)  (ws + take(256));
  (void)ws_size; (void)in_sizes; (void)n_in; (void)out_size;

  const int NB_N   = (N_NODES + 255)/256;
  const int NB_E   = (NEDGE   + 255)/256;
  const int NB_SC  = (N_NODES + 1023)/1024;
  const int NB_T64 = (N_NODES + 63)/64;
  const int NB_T128= (N_NODES + 127)/128;
  const int NB_PK  = (442368 + 98304 + 8192)/256;

  k_detect<<<1, 64, 0, stream>>>(ei, flag);
  k_zero  <<<NB_N, 256, 0, stream>>>(deg, N_NODES);
  k_deg   <<<NB_E, 256, 0, stream>>>(ei, flag, deg);
  k_scan1 <<<NB_SC, 256, 0, stream>>>(deg, rp, bsums);
  k_scan2 <<<1, 64, 0, stream>>>(bsums, NB_SC);
  k_scan3 <<<NB_N+1, 256, 0, stream>>>(rp, cur, idg, deg, bsums);
  k_fill  <<<NB_E, 256, 0, stream>>>(ei, flag, cur, col);
  k_pack  <<<NB_PK, 256, 0, stream>>>(tw, wl, wr, cw, wp, wg, cwt);

  for (int l=0; l<NLAYER; l++){
    k_convm<<<NB_T128, 256, 0, stream>>>(x, xhi, xlo, (l>0) ? 1 : 0,
                                         wp + (size_t)l*294912, tb + l*128, hhi, hlo);
    k_agg  <<<N_NODES/4, 256, 0, stream>>>(hhi, rp, col, idg, ahi, alo);
    k_gemmm<<<NB_T128, 256, 0, stream>>>(ahi, alo, hhi, hlo, wg + (size_t)l*65536,
                                         bl + l*128, bng + l*128, bnb + l*128,
                                         bnm + l*128, bnv + l*128, xhi, xlo);
  }
  k_clf<<<NB_T64, 256, 0, stream>>>(xhi, xlo, cwt, cb, out);
}

// Round 12
// 474.835 us; speedup vs baseline: 3.0671x; 1.0334x over previous
//
#include <hip/hip_runtime.h>
#include <cstddef>
#include <cstdint>

// STGCN v4: v3 + conv/gemm tiles shrunk 128->64 nodes (grid 391->782 blocks).
//   v3 PMC showed k_convm: Occupancy 12.5% (1 block/CU, grid-limited),
//   MfmaUtil 31%, HBM 9.6% -> latency-bound. 64-node tiles give ~3 blocks/CU
//   (12 waves/CU) for TLP; LDS 18.4/16 KB, acc regs halved, lb(256,4).
// Everything else identical to v3 (measured 490.7us; agg fix confirmed).

#define N_NODES 50000
#define FDIM    128
#define OUTC    64
#define NLAYER  3
#define KW      9
#define PADW    4
#define NEDGE   600000
#define BN_EPS  1e-5f

typedef short bf16x8 __attribute__((ext_vector_type(8)));
typedef float f32x4  __attribute__((ext_vector_type(4)));

__device__ __forceinline__ float relu_(float v){ return v > 0.f ? v : 0.f; }

__device__ __forceinline__ unsigned short bf_rne(float x){
  unsigned u = __float_as_uint(x);
  unsigned r = u + 0x7fff + ((u >> 16) & 1);
  return (unsigned short)(r >> 16);
}
__device__ __forceinline__ unsigned short bf_hi(float x, float& rem){
  unsigned short h = bf_rne(x);
  rem = x - __uint_as_float(((unsigned)h) << 16);
  return h;
}
__device__ __forceinline__ float bf2f(unsigned short u){
  return __uint_as_float(((unsigned)u) << 16);
}
// convert 8 floats -> packed hi int4 + lo int4 (layer-0 conv staging only)
__device__ __forceinline__ void cvt8(const float4& f0, const float4& f1, int4& hv, int4& lv){
  float f[8] = {f0.x,f0.y,f0.z,f0.w,f1.x,f1.y,f1.z,f1.w};
  unsigned short h[8], l[8];
  #pragma unroll
  for (int i=0;i<8;i++){ float r; h[i] = bf_hi(f[i], r); l[i] = bf_rne(r); }
  hv.x = (int)((unsigned)h[0] | ((unsigned)h[1]<<16));
  hv.y = (int)((unsigned)h[2] | ((unsigned)h[3]<<16));
  hv.z = (int)((unsigned)h[4] | ((unsigned)h[5]<<16));
  hv.w = (int)((unsigned)h[6] | ((unsigned)h[7]<<16));
  lv.x = (int)((unsigned)l[0] | ((unsigned)l[1]<<16));
  lv.y = (int)((unsigned)l[2] | ((unsigned)l[3]<<16));
  lv.z = (int)((unsigned)l[4] | ((unsigned)l[5]<<16));
  lv.w = (int)((unsigned)l[6] | ((unsigned)l[7]<<16));
}

// ---------------- edge dtype detect + CSR build ----------------

__global__ void k_detect(const int* __restrict__ ei, int* __restrict__ flag){
  int t = threadIdx.x;
  unsigned long long b = __ballot(ei[2*t+1] == 0);
  if (t == 0) flag[0] = (b == ~0ull) ? 1 : 0;
}

__global__ void k_zero(int* __restrict__ p, int n){
  int i = blockIdx.x*256 + threadIdx.x;
  if (i < n) p[i] = 0;
}

__global__ void k_deg(const int* __restrict__ ei, const int* __restrict__ flag, int* __restrict__ deg){
  int e = blockIdx.x*256 + threadIdx.x;
  if (e >= NEDGE) return;
  int d = flag[0] ? ei[2*(NEDGE+e)] : ei[NEDGE+e];
  atomicAdd(&deg[d], 1);
}

__global__ void k_scan1(const int* __restrict__ deg, int* __restrict__ rp, int* __restrict__ bsums){
  __shared__ int sd[256];
  int t = threadIdx.x, base = blockIdx.x*1024 + t*4;
  int v0=0,v1=0,v2=0,v3=0;
  if (base+3 < N_NODES){ int4 q = *(const int4*)(deg+base); v0=q.x; v1=q.y; v2=q.z; v3=q.w; }
  else {
    if (base   < N_NODES) v0 = deg[base];
    if (base+1 < N_NODES) v1 = deg[base+1];
    if (base+2 < N_NODES) v2 = deg[base+2];
    if (base+3 < N_NODES) v3 = deg[base+3];
  }
  int s = v0+v1+v2+v3;
  sd[t] = s; __syncthreads();
  #pragma unroll
  for (int o=1;o<256;o<<=1){
    int x = (t>=o) ? sd[t-o] : 0;
    __syncthreads();
    sd[t] += x;
    __syncthreads();
  }
  int excl = sd[t]-s;
  if (base   < N_NODES) rp[base  ] = excl;
  if (base+1 < N_NODES) rp[base+1] = excl+v0;
  if (base+2 < N_NODES) rp[base+2] = excl+v0+v1;
  if (base+3 < N_NODES) rp[base+3] = excl+v0+v1+v2;
  if (t==255) bsums[blockIdx.x] = sd[255];
}

__global__ void k_scan2(int* __restrict__ bsums, int nb){
  if (threadIdx.x==0 && blockIdx.x==0){
    int run = 0;
    for (int i=0;i<nb;i++){ int x = bsums[i]; bsums[i] = run; run += x; }
  }
}

__global__ void k_scan3(int* __restrict__ rp, int* __restrict__ cur, float* __restrict__ idg,
                        const int* __restrict__ deg, const int* __restrict__ bsums){
  int i = blockIdx.x*256 + threadIdx.x;
  if (i < N_NODES){
    int r = rp[i] + bsums[i>>10];
    rp[i] = r; cur[i] = r;
    int d = deg[i];
    idg[i] = (d>0) ? 1.0f/(float)d : 0.0f;
  } else if (i == N_NODES){
    rp[N_NODES] = NEDGE;
  }
}

__global__ void k_fill(const int* __restrict__ ei, const int* __restrict__ flag,
                       int* __restrict__ cur, int* __restrict__ col){
  int e = blockIdx.x*256 + threadIdx.x;
  if (e >= NEDGE) return;
  int s,d;
  if (flag[0]){ s = ei[2*e]; d = ei[2*(NEDGE+e)]; }
  else        { s = ei[e];   d = ei[NEDGE+e];   }
  int pos = atomicAdd(&cur[d], 1);
  col[pos] = s;
}

// ---------------- weight prepack into MFMA fragment chunks (as v2) ----------------

__global__ void k_pack(const float* __restrict__ tw, const float* __restrict__ wl,
                       const float* __restrict__ wr, const float* __restrict__ cw,
                       unsigned short* __restrict__ wp, unsigned short* __restrict__ wg,
                       float* __restrict__ cwt){
  int i = blockIdx.x*256 + threadIdx.x;
  const int T1v = 442368, T2v = 98304, T3v = 8192;
  if (i < T1v){
    int e = i & 7, lane = (i>>3)&63, ob = (i>>9)&7, cb = (i>>12)&3, kl = i>>14;
    int k = kl % KW, l = kl / KW;
    int o = ob*16 + (lane&15), c = cb*32 + (lane>>4)*8 + e;
    float v = tw[(((l*128+o)*128+c)*KW) + k];
    float rem; unsigned short hi = bf_hi(v, rem); unsigned short lo = bf_rne(rem);
    int chunk = (((l*KW+k)*4+cb)*8+ob)*2;
    wp[(size_t)chunk*512 + lane*8 + e]     = hi;
    wp[(size_t)(chunk+1)*512 + lane*8 + e] = lo;
  } else if (i < T1v+T2v){
    int i2 = i - T1v;
    int e = i2 & 7, lane = (i2>>3)&63, ob = (i2>>9)&7, ks = (i2>>12)&7, l = i2>>15;
    int o = ob*16 + (lane&15), j = ks*32 + (lane>>4)*8 + e;
    float v = (j < 128) ? wl[(l*128+o)*128 + j] : wr[(l*128+o)*128 + (j-128)];
    float rem; unsigned short hi = bf_hi(v, rem); unsigned short lo = bf_rne(rem);
    int chunk = ((l*8+ks)*8+ob)*2;
    wg[(size_t)chunk*512 + lane*8 + e]     = hi;
    wg[(size_t)(chunk+1)*512 + lane*8 + e] = lo;
  } else if (i < T1v+T2v+T3v){
    int j3 = i - (T1v+T2v);
    int o = j3 & 63, c = j3 >> 6;
    cwt[j3] = cw[o*128 + c];
  }
}

// ---------------- conv via MFMA: 64-node x 128-out tile, 4 waves ----------------
// wave w -> cols [w*32, w*32+32); per-wave output 64x32 (acc[4][2] f32x4).
// K = 9 taps x 128 ch as two 64-ch LDS halves (hi/lo planes, XOR-swizzled).

#define CROWS 72

__global__ __launch_bounds__(256, 4) void k_convm(const float* __restrict__ xf,
                                                  const unsigned short* __restrict__ xhi,
                                                  const unsigned short* __restrict__ xlo,
                                                  const int use_planes,
                                                  const unsigned short* __restrict__ wpl,
                                                  const float* __restrict__ tb,
                                                  unsigned short* __restrict__ hhi,
                                                  unsigned short* __restrict__ hlo){
  __shared__ unsigned short sh[2*CROWS*64];     // 18432 B
  const int t = threadIdx.x;
  const int n0 = blockIdx.x*64;
  const int l = t & 63, w = t >> 6;
  const int l15 = l & 15, kg = l >> 4;
  const bf16x8* Bp = (const bf16x8*)wpl;

  f32x4 acc[4][2];
  #pragma unroll
  for (int rf=0;rf<4;rf++){ acc[rf][0] = (f32x4)0.f; acc[rf][1] = (f32x4)0.f; }

  bf16x8 B00, B01, B10, B11;
  {
    int ch = ((0*4+0)*8 + 2*w)*2;
    B00 = Bp[ch*64 + l]; B01 = Bp[(ch+1)*64 + l];
    B10 = Bp[(ch+2)*64 + l]; B11 = Bp[(ch+3)*64 + l];
  }

  for (int half = 0; half < 2; ++half){
    if (half) __syncthreads();
    for (int u = t; u < CROWS*8; u += 256){
      int row = u >> 3, c8 = u & 7;
      int gn = n0 - PADW + row;
      int4 hv = make_int4(0,0,0,0), lv = make_int4(0,0,0,0);
      if (gn >= 0 && gn < N_NODES){
        if (use_planes){
          size_t o = (size_t)gn*FDIM + half*64 + c8*8;
          hv = *(const int4*)(xhi + o);
          lv = *(const int4*)(xlo + o);
        } else {
          const float* src = xf + (size_t)gn*FDIM + half*64 + c8*8;
          float4 f0 = *(const float4*)src, f1 = *(const float4*)(src+4);
          cvt8(f0, f1, hv, lv);
        }
      }
      int idx = row*64 + ((c8 ^ (row&7)) << 3);
      *(int4*)&sh[idx] = hv;
      *(int4*)&sh[CROWS*64 + idx] = lv;
    }
    __syncthreads();

    for (int kk = 0; kk < 18; ++kk){
      int k = kk >> 1, cb2 = kk & 1;
      bf16x8 Bc00=B00, Bc01=B01, Bc10=B10, Bc11=B11;
      {
        int it = half*18 + kk;
        int itn = (it+1 < 36) ? it+1 : it;
        int halfn = itn/18, kkn = itn%18;
        int kn = kkn>>1, cb2n = kkn&1, cbgn = halfn*2 + cb2n;
        int ch = ((kn*4+cbgn)*8 + 2*w)*2;
        B00 = Bp[ch*64 + l]; B01 = Bp[(ch+1)*64 + l];
        B10 = Bp[(ch+2)*64 + l]; B11 = Bp[(ch+3)*64 + l];
      }
      int cc3 = cb2*4 + kg;
      int swz = ((cc3 ^ ((l15 + k) & 7)) << 3);  // row&7 == (l15+k)&7 (rf*16 ≡ 0 mod 8)
      int base = (l15 + k)*64 + swz;
      #pragma unroll
      for (int rf = 0; rf < 4; ++rf){
        int idx = base + rf*16*64;
        bf16x8 Ah = *(const bf16x8*)&sh[idx];
        bf16x8 Al = *(const bf16x8*)&sh[CROWS*64 + idx];
        acc[rf][0] = __builtin_amdgcn_mfma_f32_16x16x32_bf16(Ah, Bc00, acc[rf][0], 0,0,0);
        acc[rf][0] = __builtin_amdgcn_mfma_f32_16x16x32_bf16(Ah, Bc01, acc[rf][0], 0,0,0);
        acc[rf][0] = __builtin_amdgcn_mfma_f32_16x16x32_bf16(Al, Bc00, acc[rf][0], 0,0,0);
        acc[rf][1] = __builtin_amdgcn_mfma_f32_16x16x32_bf16(Ah, Bc10, acc[rf][1], 0,0,0);
        acc[rf][1] = __builtin_amdgcn_mfma_f32_16x16x32_bf16(Ah, Bc11, acc[rf][1], 0,0,0);
        acc[rf][1] = __builtin_amdgcn_mfma_f32_16x16x32_bf16(Al, Bc10, acc[rf][1], 0,0,0);
      }
    }
  }

  int o0 = w*32 + l15, o1 = o0 + 16;
  float tb0 = tb[o0], tb1 = tb[o1];
  #pragma unroll
  for (int rf = 0; rf < 4; ++rf){
    #pragma unroll
    for (int j = 0; j < 4; ++j){
      int n = n0 + rf*16 + kg*4 + j;
      if (n < N_NODES){
        float v0 = relu_(acc[rf][0][j] + tb0);
        float v1 = relu_(acc[rf][1][j] + tb1);
        float r0, r1;
        unsigned short h0 = bf_hi(v0, r0), h1 = bf_hi(v1, r1);
        size_t b = (size_t)n*FDIM;
        hhi[b+o0] = h0; hlo[b+o0] = bf_rne(r0);
        hhi[b+o1] = h1; hlo[b+o1] = bf_rne(r1);
      }
    }
  }
}

// ---------------- SAGE mean aggregation: bf16-hi gather (as v3) ----------------

__global__ __launch_bounds__(256) void k_agg(const unsigned short* __restrict__ hhi,
                                             const int* __restrict__ rp,
                                             const int* __restrict__ col,
                                             const float* __restrict__ idg,
                                             unsigned short* __restrict__ ahi,
                                             unsigned short* __restrict__ alo){
  int n = blockIdx.x*4 + (threadIdx.x>>6);
  int lane = threadIdx.x & 63;
  int half = lane >> 5, li = lane & 31;
  if (n >= N_NODES) return;
  int s0 = rp[n], s1 = rp[n+1];
  float a0=0.f, a1=0.f, a2=0.f, a3=0.f;
  int e = s0 + half;
  for (; e + 2 < s1; e += 4){
    int sA = col[e], sB = col[e+2];
    ushort4 vA = *(const ushort4*)(hhi + (size_t)sA*FDIM + li*4);
    ushort4 vB = *(const ushort4*)(hhi + (size_t)sB*FDIM + li*4);
    a0 += bf2f(vA.x) + bf2f(vB.x);
    a1 += bf2f(vA.y) + bf2f(vB.y);
    a2 += bf2f(vA.z) + bf2f(vB.z);
    a3 += bf2f(vA.w) + bf2f(vB.w);
  }
  for (; e < s1; e += 2){
    int s = col[e];
    ushort4 v = *(const ushort4*)(hhi + (size_t)s*FDIM + li*4);
    a0 += bf2f(v.x); a1 += bf2f(v.y); a2 += bf2f(v.z); a3 += bf2f(v.w);
  }
  a0 += __shfl_xor(a0, 32);
  a1 += __shfl_xor(a1, 32);
  a2 += __shfl_xor(a2, 32);
  a3 += __shfl_xor(a3, 32);
  float wv = idg[n];
  a0 *= wv; a1 *= wv; a2 *= wv; a3 *= wv;
  float r0,r1,r2,r3;
  unsigned short h0 = bf_hi(a0,r0), h1 = bf_hi(a1,r1), h2 = bf_hi(a2,r2), h3 = bf_hi(a3,r3);
  size_t b = (size_t)n*FDIM + li*4;
  if (half == 0){
    ushort4 o; o.x=h0; o.y=h1; o.z=h2; o.w=h3;
    *(ushort4*)(ahi + b) = o;
  } else {
    ushort4 o; o.x=bf_rne(r0); o.y=bf_rne(r1); o.z=bf_rne(r2); o.w=bf_rne(r3);
    *(ushort4*)(alo + b) = o;
  }
}

// ---------------- SAGE linear + BN + ReLU via MFMA: 64-node tile ----------------

__global__ __launch_bounds__(256, 4) void k_gemmm(const unsigned short* __restrict__ ahi,
                                                  const unsigned short* __restrict__ alo,
                                                  const unsigned short* __restrict__ hhi,
                                                  const unsigned short* __restrict__ hlo,
                                                  const unsigned short* __restrict__ wgl,
                                                  const float* __restrict__ bl,
                                                  const float* __restrict__ bng, const float* __restrict__ bnb,
                                                  const float* __restrict__ bnm, const float* __restrict__ bnv,
                                                  unsigned short* __restrict__ xhi,
                                                  unsigned short* __restrict__ xlo){
  __shared__ unsigned short sh[2*64*64];        // 16384 B
  const int t = threadIdx.x;
  const int n0 = blockIdx.x*64;
  const int l = t & 63, w = t >> 6;
  const int l15 = l & 15, kg = l >> 4;
  const bf16x8* Bp = (const bf16x8*)wgl;

  f32x4 acc[4][2];
  #pragma unroll
  for (int rf=0;rf<4;rf++){ acc[rf][0] = (f32x4)0.f; acc[rf][1] = (f32x4)0.f; }

  bf16x8 B00, B01, B10, B11;
  {
    int ch = (0*8 + 2*w)*2;
    B00 = Bp[ch*64 + l]; B01 = Bp[(ch+1)*64 + l];
    B10 = Bp[(ch+2)*64 + l]; B11 = Bp[(ch+3)*64 + l];
  }

  for (int p = 0; p < 4; ++p){
    if (p) __syncthreads();
    const unsigned short* shi = (p >= 2) ? hhi : ahi;
    const unsigned short* slo = (p >= 2) ? hlo : alo;
    int ch0 = (p & 1)*64;
    for (int u = t; u < 64*8; u += 256){
      int row = u >> 3, c8 = u & 7;
      int gn = n0 + row;
      int4 hv = make_int4(0,0,0,0), lv = make_int4(0,0,0,0);
      if (gn < N_NODES){
        size_t o = (size_t)gn*FDIM + ch0 + c8*8;
        hv = *(const int4*)(shi + o);
        lv = *(const int4*)(slo + o);
      }
      int idx = row*64 + ((c8 ^ (row&7)) << 3);
      *(int4*)&sh[idx] = hv;
      *(int4*)&sh[64*64 + idx] = lv;
    }
    __syncthreads();

    for (int cb2 = 0; cb2 < 2; ++cb2){
      bf16x8 Bc00=B00, Bc01=B01, Bc10=B10, Bc11=B11;
      {
        int ks = p*2 + cb2;
        int ksn = (ks+1 < 8) ? ks+1 : ks;
        int ch = (ksn*8 + 2*w)*2;
        B00 = Bp[ch*64 + l]; B01 = Bp[(ch+1)*64 + l];
        B10 = Bp[(ch+2)*64 + l]; B11 = Bp[(ch+3)*64 + l];
      }
      int cc3 = cb2*4 + kg;
      int swz = ((cc3 ^ (l15 & 7)) << 3);
      int base = l15*64 + swz;
      #pragma unroll
      for (int rf = 0; rf < 4; ++rf){
        int idx = base + rf*16*64;
        bf16x8 Ah = *(const bf16x8*)&sh[idx];
        bf16x8 Al = *(const bf16x8*)&sh[64*64 + idx];
        acc[rf][0] = __builtin_amdgcn_mfma_f32_16x16x32_bf16(Ah, Bc00, acc[rf][0], 0,0,0);
        acc[rf][0] = __builtin_amdgcn_mfma_f32_16x16x32_bf16(Ah, Bc01, acc[rf][0], 0,0,0);
        acc[rf][0] = __builtin_amdgcn_mfma_f32_16x16x32_bf16(Al, Bc00, acc[rf][0], 0,0,0);
        acc[rf][1] = __builtin_amdgcn_mfma_f32_16x16x32_bf16(Ah, Bc10, acc[rf][1], 0,0,0);
        acc[rf][1] = __builtin_amdgcn_mfma_f32_16x16x32_bf16(Ah, Bc11, acc[rf][1], 0,0,0);
        acc[rf][1] = __builtin_amdgcn_mfma_f32_16x16x32_bf16(Al, Bc10, acc[rf][1], 0,0,0);
      }
    }
  }

  int o0 = w*32 + l15, o1 = o0 + 16;
  float s0 = bng[o0]*rsqrtf(bnv[o0]+BN_EPS);
  float c0 = bnb[o0] + s0*(bl[o0]-bnm[o0]);
  float s1 = bng[o1]*rsqrtf(bnv[o1]+BN_EPS);
  float c1 = bnb[o1] + s1*(bl[o1]-bnm[o1]);
  #pragma unroll
  for (int rf = 0; rf < 4; ++rf){
    #pragma unroll
    for (int j = 0; j < 4; ++j){
      int n = n0 + rf*16 + kg*4 + j;
      if (n < N_NODES){
        float v0 = relu_(s0*acc[rf][0][j] + c0);
        float v1 = relu_(s1*acc[rf][1][j] + c1);
        float r0, r1;
        unsigned short h0 = bf_hi(v0, r0), h1 = bf_hi(v1, r1);
        size_t b = (size_t)n*FDIM;
        xhi[b+o0] = h0; xlo[b+o0] = bf_rne(r0);
        xhi[b+o1] = h1; xlo[b+o1] = bf_rne(r1);
      }
    }
  }
}

// ---------------- classifier + log_softmax (reads hi/lo planes, as v3) ----------------

__global__ __launch_bounds__(256) void k_clf(const unsigned short* __restrict__ xhi,
                                             const unsigned short* __restrict__ xlo,
                                             const float* __restrict__ cwt,
                                             const float* __restrict__ cb, float* __restrict__ out){
  __shared__ float As[128][68];
  __shared__ float mxl[64];
  const int t = threadIdx.x, n0 = blockIdx.x*64;
  const int ng = t & 15, og = t>>4;
  float acc[4][4];
  #pragma unroll
  for (int i=0;i<4;i++)
    #pragma unroll
    for (int j=0;j<4;j++) acc[i][j] = 0.f;

  for (int u=t; u<64*16; u+=256){
    int row = u>>4, c16 = u&15;
    int gn = n0 + row;
    int4 hv = make_int4(0,0,0,0), lv = make_int4(0,0,0,0);
    if (gn < N_NODES){
      size_t o = (size_t)gn*FDIM + c16*8;
      hv = *(const int4*)(xhi + o);
      lv = *(const int4*)(xlo + o);
    }
    const unsigned short* hs = (const unsigned short*)&hv;
    const unsigned short* ls = (const unsigned short*)&lv;
    #pragma unroll
    for (int j=0;j<8;j++) As[c16*8+j][row] = bf2f(hs[j]) + bf2f(ls[j]);
  }
  __syncthreads();
  #pragma unroll 2
  for (int c=0;c<128;c++){
    float aa[4] = {As[c][ng], As[c][ng+16], As[c][ng+32], As[c][ng+48]};
    float4 b = *(const float4*)(cwt + c*64 + og*4);
    float bb[4] = {b.x,b.y,b.z,b.w};
    #pragma unroll
    for (int i=0;i<4;i++)
      #pragma unroll
      for (int j=0;j<4;j++) acc[i][j] = fmaf(aa[i], bb[j], acc[i][j]);
  }
  __syncthreads();
  float4 cb4 = *(const float4*)(cb + og*4);
  float cbv[4] = {cb4.x,cb4.y,cb4.z,cb4.w};
  #pragma unroll
  for (int i=0;i<4;i++)
    #pragma unroll
    for (int j=0;j<4;j++) As[ng+16*i][og*4+j] = acc[i][j] + cbv[j];
  __syncthreads();
  if (t < 64){
    float mx = -1e30f;
    #pragma unroll 8
    for (int o=0;o<64;o++) mx = fmaxf(mx, As[t][o]);
    float se = 0.f;
    #pragma unroll 8
    for (int o=0;o<64;o++) se += expf(As[t][o]-mx);
    mxl[t] = mx + logf(se);
  }
  __syncthreads();
  #pragma unroll
  for (int v=0;v<4;v++){
    int q = t + v*256;
    int r = q>>4, o4 = (q&15)*4;
    int n = n0 + r;
    if (n < N_NODES){
      float4 L = *(const float4*)&As[r][o4];
      float m = mxl[r];
      float4 wv; wv.x = L.x-m; wv.y = L.y-m; wv.z = L.z-m; wv.w = L.w-m;
      *(float4*)(out + (size_t)n*OUTC + o4) = wv;
    }
  }
}

// ---------------- launch ----------------

extern "C" void kernel_launch(void* const* d_in, const int* in_sizes, int n_in,
                              void* d_out, int out_size, void* d_ws, size_t ws_size,
                              hipStream_t stream) {
  const float* x   = (const float*)d_in[0];
  const int*   ei  = (const int*)  d_in[1];
  const float* tw  = (const float*)d_in[2];
  const float* tb  = (const float*)d_in[3];
  const float* wl  = (const float*)d_in[4];
  const float* bl  = (const float*)d_in[5];
  const float* wr  = (const float*)d_in[6];
  const float* bng = (const float*)d_in[7];
  const float* bnb = (const float*)d_in[8];
  const float* bnm = (const float*)d_in[9];
  const float* bnv = (const float*)d_in[10];
  const float* cw  = (const float*)d_in[11];
  const float* cb  = (const float*)d_in[12];
  float* out = (float*)d_out;
  char* ws = (char*)d_ws;

  auto align256 = [](size_t v){ return (v + 255) & ~(size_t)255; };
  size_t off = 0;
  auto take = [&](size_t bytes){ size_t o = off; off += align256(bytes); return o; };
  const size_t PLANE = (size_t)N_NODES*FDIM*2;              // 12.8 MB
  unsigned short* xhi = (unsigned short*)(ws + take(PLANE));
  unsigned short* xlo = (unsigned short*)(ws + take(PLANE));
  unsigned short* hhi = (unsigned short*)(ws + take(PLANE));
  unsigned short* hlo = (unsigned short*)(ws + take(PLANE));
  unsigned short* ahi = (unsigned short*)(ws + take(PLANE));
  unsigned short* alo = (unsigned short*)(ws + take(PLANE));
  unsigned short* wp  = (unsigned short*)(ws + take((size_t)884736*2));
  unsigned short* wg  = (unsigned short*)(ws + take((size_t)196608*2));
  float* cwt   = (float*)(ws + take((size_t)128*64*4));
  int*   deg   = (int*)  (ws + take((size_t)N_NODES*4));
  int*   rp    = (int*)  (ws + take((size_t)(N_NODES+1)*4));
  int*   cur   = (int*)  (ws + take((size_t)N_NODES*4));
  int*   col   = (int*)  (ws + take((size_t)NEDGE*4));
  float* idg   = (float*)(ws + take((size_t)N_NODES*4));
  int*   bsums = (int*)  (ws + take(256));
  int*   flag  = (int*)  (ws + take(256));
  (void)ws_size; (void)in_sizes; (void)n_in; (void)out_size;

  const int NB_N   = (N_NODES + 255)/256;
  const int NB_E   = (NEDGE   + 255)/256;
  const int NB_SC  = (N_NODES + 1023)/1024;
  const int NB_T64 = (N_NODES + 63)/64;     // 782 (conv/gemm/clf)
  const int NB_PK  = (442368 + 98304 + 8192)/256;

  k_detect<<<1, 64, 0, stream>>>(ei, flag);
  k_zero  <<<NB_N, 256, 0, stream>>>(deg, N_NODES);
  k_deg   <<<NB_E, 256, 0, stream>>>(ei, flag, deg);
  k_scan1 <<<NB_SC, 256, 0, stream>>>(deg, rp, bsums);
  k_scan2 <<<1, 64, 0, stream>>>(bsums, NB_SC);
  k_scan3 <<<NB_N+1, 256, 0, stream>>>(rp, cur, idg, deg, bsums);
  k_fill  <<<NB_E, 256, 0, stream>>>(ei, flag, cur, col);
  k_pack  <<<NB_PK, 256, 0, stream>>>(tw, wl, wr, cw, wp, wg, cwt);

  for (int l=0; l<NLAYER; l++){
    k_convm<<<NB_T64, 256, 0, stream>>>(x, xhi, xlo, (l>0) ? 1 : 0,
                                        wp + (size_t)l*294912, tb + l*128, hhi, hlo);
    k_agg  <<<N_NODES/4, 256, 0, stream>>>(hhi, rp, col, idg, ahi, alo);
    k_gemmm<<<NB_T64, 256, 0, stream>>>(ahi, alo, hhi, hlo, wg + (size_t)l*65536,
                                        bl + l*128, bng + l*128, bnb + l*128,
                                        bnm + l*128, bnv + l*128, xhi, xlo);
  }
  k_clf<<<NB_T64, 256, 0, stream>>>(xhi, xlo, cwt, cb, out);
}